// Round 7
// baseline (54723.590 us; speedup 1.0000x reference)
//
#include <hip/hip_runtime.h>

typedef short bf16x8 __attribute__((ext_vector_type(8)));
typedef float f32x4 __attribute__((ext_vector_type(4)));

#define HID   512
#define DXD   256
#define DYD   64
#define NROWS 32
#define NTHR  512
#define LRC   0.1f
#define TAU1  1e-4f
#define TAU2  1e-4f

// ws element offsets (u16) within one plane; planes: hi, +WS_ELEMS mid, +2*WS_ELEMS lo
#define OFF_W1XB 0          // [512][256]  (unused by main kernel now; kept for table layout stability)
#define OFF_W1YB 131072     // [512][64]   W1yB[n][k] = W1[(256+k)*512+n]
#define OFF_W1Y4 163840     // [64][512]   W1y4[d][j] = W1[(256+d)*512+j]
#define OFF_W2B  196608     // [512][512]  W2B[n][k]  = W2[k*512+n]
#define OFF_W2B3 458752     // [512][512]  W2B3[n][k] = W2[n*512+k]
#define WS_ELEMS 720896

// LDS layout (bytes)
#define L_A0  0             // act plane hi  [32][512]*2B, row stride 1024; x_f32 [32][256]*4B during stage0
#define L_A1  32768         // act plane mid
#define L_A2  65536         // act plane lo
#define APL   32768
#define L_Y0  98304         // y plane hi [32][64]*2B, row stride 128
#define L_Y1  102400
#define L_Y2  106496
#define YPL   4096
#define L_TL  110592
#define SMEM_BYTES 110848

__device__ __forceinline__ unsigned short f2bf(float f) {
    unsigned u = __float_as_uint(f);
    u = (u + 0x7FFFu + ((u >> 16) & 1u)) >> 16;   // RNE
    return (unsigned short)u;
}
__device__ __forceinline__ float bf2f(unsigned short u) {
    return __uint_as_float(((unsigned)u) << 16);
}

template<int PS>
__device__ __forceinline__ void store3(char* base, int off, float v) {
    unsigned short h = f2bf(v);
    float r1 = v - bf2f(h);
    unsigned short m = f2bf(r1);
    float r2 = r1 - bf2f(m);
    *(unsigned short*)(base + off)          = h;
    *(unsigned short*)(base + PS + off)     = m;
    *(unsigned short*)(base + 2 * PS + off) = f2bf(r2);
}

// 2x4 tile GEMM, 3-plane split-bf16, 6 exact-product terms into ONE fp32 acc.
template<int KSTEPS, int SROWA, int KDIM, int APL_>
__device__ __forceinline__ void gemm6(const char* ldsA, const unsigned short* B,
                                      int l4, int l16, int nt0, f32x4 acc[2][4])
{
    const int cb0 = l4 * 16;
    #pragma unroll
    for (int kk = 0; kk < KSTEPS; ++kk) {
        const int cb = kk * 64 + cb0;
        bf16x8 a0[2], a1_[2], a2_[2], b0[4], b1_[4], b2_[4];
        #pragma unroll
        for (int mt = 0; mt < 2; ++mt) {
            const int row = mt * 16 + l16;
            const int off = row * SROWA + (cb ^ ((row & 7) << 4));
            a0[mt]  = *(const bf16x8*)(ldsA + off);
            a1_[mt] = *(const bf16x8*)(ldsA + APL_ + off);
            a2_[mt] = *(const bf16x8*)(ldsA + 2 * APL_ + off);
        }
        #pragma unroll
        for (int nq = 0; nq < 4; ++nq) {
            const size_t off = (size_t)((nt0 + nq) * 16 + l16) * (KDIM * 2) + cb;
            b0[nq]  = *(const bf16x8*)((const char*)B + off);
            b1_[nq] = *(const bf16x8*)((const char*)(B + WS_ELEMS) + off);
            b2_[nq] = *(const bf16x8*)((const char*)(B + 2 * WS_ELEMS) + off);
        }
        #pragma unroll
        for (int mt = 0; mt < 2; ++mt)
            #pragma unroll
            for (int nq = 0; nq < 4; ++nq) {
                acc[mt][nq] = __builtin_amdgcn_mfma_f32_16x16x32_bf16(a0[mt],  b0[nq],  acc[mt][nq], 0, 0, 0);
                acc[mt][nq] = __builtin_amdgcn_mfma_f32_16x16x32_bf16(a0[mt],  b1_[nq], acc[mt][nq], 0, 0, 0);
                acc[mt][nq] = __builtin_amdgcn_mfma_f32_16x16x32_bf16(a1_[mt], b0[nq],  acc[mt][nq], 0, 0, 0);
                acc[mt][nq] = __builtin_amdgcn_mfma_f32_16x16x32_bf16(a0[mt],  b2_[nq], acc[mt][nq], 0, 0, 0);
                acc[mt][nq] = __builtin_amdgcn_mfma_f32_16x16x32_bf16(a2_[mt], b0[nq],  acc[mt][nq], 0, 0, 0);
                acc[mt][nq] = __builtin_amdgcn_mfma_f32_16x16x32_bf16(a1_[mt], b1_[nq], acc[mt][nq], 0, 0, 0);
            }
    }
}

// Serial fp32 recompute of a2[row][col] (np-matching j-ascending fmaf chain).
__device__ __attribute__((noinline))
float rescue_s2(const char* smem, int row, int col, float b2n, const float* __restrict__ W2) {
    float r = b2n;
    const int xr = (row & 7) << 4;
    const int rb = row * 1024;
    for (int j0 = 0; j0 < HID; j0 += 8) {
        const int off = rb + ((j0 * 2) ^ xr);
        bf16x8 h  = *(const bf16x8*)(smem + L_A0 + off);
        bf16x8 m_ = *(const bf16x8*)(smem + L_A1 + off);
        bf16x8 l  = *(const bf16x8*)(smem + L_A2 + off);
        #pragma unroll
        for (int u = 0; u < 8; ++u) {
            float hv = (bf2f((unsigned short)h[u]) + bf2f((unsigned short)m_[u])) + bf2f((unsigned short)l[u]);
            r = fmaf(hv, W2[(size_t)(j0 + u) * HID + col], r);
        }
    }
    return r;
}

// Serial fp32 recompute of a1[row][col] from exact c and LDS y planes.
__device__ __attribute__((noinline))
float rescue_s1(const char* smem, int row, int col, float cval, const float* __restrict__ W1) {
    float r = cval;
    const int xr = (row & 7) << 4;
    const int rb = row * 128;
    for (int j0 = 0; j0 < DYD; j0 += 8) {
        const int off = rb + ((j0 * 2) ^ xr);
        bf16x8 h  = *(const bf16x8*)(smem + L_Y0 + off);
        bf16x8 m_ = *(const bf16x8*)(smem + L_Y1 + off);
        bf16x8 l  = *(const bf16x8*)(smem + L_Y2 + off);
        #pragma unroll
        for (int u = 0; u < 8; ++u) {
            float yv = (bf2f((unsigned short)h[u]) + bf2f((unsigned short)m_[u])) + bf2f((unsigned short)l[u]);
            r = fmaf(yv, W1[(size_t)(DXD + j0 + u) * HID + col], r);
        }
    }
    return r;
}

__global__ void wconv(const float* __restrict__ W1, const float* __restrict__ W2,
                      unsigned short* __restrict__ wsb)
{
    int i = blockIdx.x * blockDim.x + threadIdx.x;
    if (i >= WS_ELEMS) return;
    float v;
    if (i < OFF_W1YB)      { int n = i >> 8,               k = i & 255;  v = W1[k * 512 + n]; }
    else if (i < OFF_W1Y4) { int j = i - OFF_W1YB, n = j >> 6, k = j & 63;  v = W1[(256 + k) * 512 + n]; }
    else if (i < OFF_W2B)  { int j = i - OFF_W1Y4, d = j >> 9, k = j & 511; v = W1[(256 + d) * 512 + k]; }
    else if (i < OFF_W2B3) { int j = i - OFF_W2B,  n = j >> 9, k = j & 511; v = W2[k * 512 + n]; }
    else                   { int j = i - OFF_W2B3, n = j >> 9, k = j & 511; v = W2[n * 512 + k]; }
    unsigned short h = f2bf(v);
    float r1 = v - bf2f(h);
    unsigned short m = f2bf(r1);
    float r2 = r1 - bf2f(m);
    wsb[i]                = h;
    wsb[i + WS_ELEMS]     = m;
    wsb[i + 2 * WS_ELEMS] = f2bf(r2);
}

__global__ __launch_bounds__(NTHR, 2)
void ebm_mfma(const float* __restrict__ x, const int* __restrict__ tt,
              const float* __restrict__ W1, const float* __restrict__ b1,
              const float* __restrict__ W2, const float* __restrict__ b2,
              const float* __restrict__ W3, const int* __restrict__ stepsp,
              const unsigned short* __restrict__ wsb, float* __restrict__ out)
{
    extern __shared__ char smem[];

    const int tid  = threadIdx.x;
    const int w    = tid >> 6, lane = tid & 63;
    const int l4   = lane >> 4, l16 = lane & 15;
    const int r0   = blockIdx.x * NROWS;
    const int nt0  = w * 4;
    const int nsteps = *stepsp;

    if (tid < NROWS) {
        int tv = tt[r0 + tid];
        ((int*)(smem + L_TL))[tid] = tv < 0 ? 0 : tv;
    }
    // zero y planes (3 * 4KB contiguous)
    for (int i = tid; i < 3 * YPL / 4; i += NTHR) ((unsigned*)(smem + L_Y0))[i] = 0u;

    // stage x -> fp32 [32][256] (row stride 1024B) in plane0 region (used only by stage0)
    {
        const float4* xg = (const float4*)(x + (size_t)r0 * DXD);
        #pragma unroll
        for (int j = 0; j < 4; ++j) {
            int i4 = j * NTHR + tid;          // 2048 float4 = 32 rows * 64
            ((float4*)(smem + L_A0))[i4] = xg[i4];
        }
    }
    __syncthreads();

    // ---- stage 0: c = x @ W1x + b1 in EXACT fp32 VALU (chain identical to the passing r6 kernel)
    f32x4 c_reg[2][4];
    {
        float bb[4];
        #pragma unroll
        for (int nq = 0; nq < 4; ++nq) bb[nq] = b1[(nt0 + nq) * 16 + l16];
        #pragma unroll
        for (int mt = 0; mt < 2; ++mt)
            #pragma unroll
            for (int nq = 0; nq < 4; ++nq)
                c_reg[mt][nq] = (f32x4){bb[nq], bb[nq], bb[nq], bb[nq]};
        for (int i = 0; i < DXD; i += 4) {
            float wv[4][4];
            #pragma unroll
            for (int d = 0; d < 4; ++d)
                #pragma unroll
                for (int nq = 0; nq < 4; ++nq)
                    wv[d][nq] = W1[(size_t)(i + d) * HID + (nt0 + nq) * 16 + l16];
            #pragma unroll
            for (int mt = 0; mt < 2; ++mt)
                #pragma unroll
                for (int q = 0; q < 4; ++q) {
                    const int row = mt * 16 + l4 * 4 + q;
                    float4 xv = *(const float4*)(smem + L_A0 + row * 1024 + i * 4);
                    #pragma unroll
                    for (int nq = 0; nq < 4; ++nq) {
                        c_reg[mt][nq][q] = fmaf(xv.x, wv[0][nq], c_reg[mt][nq][q]);
                        c_reg[mt][nq][q] = fmaf(xv.y, wv[1][nq], c_reg[mt][nq][q]);
                        c_reg[mt][nq][q] = fmaf(xv.z, wv[2][nq], c_reg[mt][nq][q]);
                        c_reg[mt][nq][q] = fmaf(xv.w, wv[3][nq], c_reg[mt][nq][q]);
                    }
                }
        }
    }

    float b2v[4];
    #pragma unroll
    for (int nq = 0; nq < 4; ++nq) b2v[nq] = b2[(nt0 + nq) * 16 + l16];

    const int mt4 = w & 1;             // S4 tile: rows mt4*16.., cols nt4*16..
    const int nt4 = w >> 1;
    f32x4 ym = (f32x4){0.f, 0.f, 0.f, 0.f};   // fp32 y master fragment

    for (int s = 0; s < nsteps; ++s) {
        __syncthreads();   // prev S4 act reads + y writes done (also fences stage0 x reads)

        // ---- S1: a1 = c + y @ W1y ; rescue ties ; h1 = relu -> act planes ; mask in regs
        f32x4 acc[2][4];
        #pragma unroll
        for (int mt = 0; mt < 2; ++mt)
            #pragma unroll
            for (int nq = 0; nq < 4; ++nq)
                acc[mt][nq] = c_reg[mt][nq];
        gemm6<2, 128, 64, YPL>(smem + L_Y0, wsb + OFF_W1YB, l4, l16, nt0, acc);

        unsigned mk = 0u;
        #pragma unroll
        for (int mt = 0; mt < 2; ++mt) {
            #pragma unroll
            for (int nq = 0; nq < 4; ++nq) {
                const int col = (nt0 + nq) * 16 + l16;
                #pragma unroll
                for (int q = 0; q < 4; ++q) {
                    const int row = mt * 16 + l4 * 4 + q;
                    float v = acc[mt][nq][q];
                    if (fabsf(v) < TAU1)
                        v = rescue_s1(smem, row, col, c_reg[mt][nq][q], W1);
                    const int off = row * 1024 + ((col * 2) ^ ((row & 7) << 4));
                    if (v > 0.f) {
                        mk |= 1u << ((mt * 4 + nq) * 4 + q);
                        store3<APL>(smem + L_A0, off, v);
                    } else {
                        *(unsigned short*)(smem + L_A0 + off) = 0;
                        *(unsigned short*)(smem + L_A1 + off) = 0;
                        *(unsigned short*)(smem + L_A2 + off) = 0;
                    }
                }
            }
        }
        __syncthreads();

        // ---- S2: a2 = h1 @ W2 + b2 ; rescue ties (reads h1 planes BEFORE they're overwritten)
        #pragma unroll
        for (int mt = 0; mt < 2; ++mt)
            #pragma unroll
            for (int nq = 0; nq < 4; ++nq)
                acc[mt][nq] = (f32x4){b2v[nq], b2v[nq], b2v[nq], b2v[nq]};
        gemm6<16, 1024, 512, APL>(smem + L_A0, wsb + OFF_W2B, l4, l16, nt0, acc);

        unsigned pos2 = 0u;
        #pragma unroll
        for (int mt = 0; mt < 2; ++mt) {
            #pragma unroll
            for (int nq = 0; nq < 4; ++nq) {
                const int col = (nt0 + nq) * 16 + l16;
                #pragma unroll
                for (int q = 0; q < 4; ++q) {
                    const int row = mt * 16 + l4 * 4 + q;
                    float v = acc[mt][nq][q];
                    if (fabsf(v) < TAU2)
                        v = rescue_s2(smem, row, col, b2v[nq], W2);
                    if (v > 0.f) pos2 |= 1u << ((mt * 4 + nq) * 4 + q);
                }
            }
        }
        __syncthreads();   // all h1 reads (gemm + rescue) done

        // S2 epi: m2 = pos ? W3[col][t_row] : 0 -> act planes (value is EXACT gather)
        #pragma unroll
        for (int mt = 0; mt < 2; ++mt) {
            #pragma unroll
            for (int nq = 0; nq < 4; ++nq) {
                const int col = (nt0 + nq) * 16 + l16;
                #pragma unroll
                for (int q = 0; q < 4; ++q) {
                    const int row = mt * 16 + l4 * 4 + q;
                    const int tv = ((const int*)(smem + L_TL))[row];
                    const int off = row * 1024 + ((col * 2) ^ ((row & 7) << 4));
                    if ((pos2 >> ((mt * 4 + nq) * 4 + q)) & 1u) {
                        store3<APL>(smem + L_A0, off, W3[col * 4 + tv]);
                    } else {
                        *(unsigned short*)(smem + L_A0 + off) = 0;
                        *(unsigned short*)(smem + L_A1 + off) = 0;
                        *(unsigned short*)(smem + L_A2 + off) = 0;
                    }
                }
            }
        }
        __syncthreads();

        // ---- S3: g2 = m2 @ W2^T (no new decisions; masked by mk)
        #pragma unroll
        for (int mt = 0; mt < 2; ++mt)
            #pragma unroll
            for (int nq = 0; nq < 4; ++nq)
                acc[mt][nq] = (f32x4){0.f, 0.f, 0.f, 0.f};
        gemm6<16, 1024, 512, APL>(smem + L_A0, wsb + OFF_W2B3, l4, l16, nt0, acc);
        __syncthreads();   // all m2 reads done

        // S3 epi: m1 = mask1 ? g2 : 0 -> act planes
        #pragma unroll
        for (int mt = 0; mt < 2; ++mt) {
            #pragma unroll
            for (int nq = 0; nq < 4; ++nq) {
                const int col2 = ((nt0 + nq) * 16 + l16) * 2;
                #pragma unroll
                for (int q = 0; q < 4; ++q) {
                    const int row = mt * 16 + l4 * 4 + q;
                    const int off = row * 1024 + (col2 ^ ((row & 7) << 4));
                    if ((mk >> ((mt * 4 + nq) * 4 + q)) & 1u) {
                        store3<APL>(smem + L_A0, off, acc[mt][nq][q]);
                    } else {
                        *(unsigned short*)(smem + L_A0 + off) = 0;
                        *(unsigned short*)(smem + L_A1 + off) = 0;
                        *(unsigned short*)(smem + L_A2 + off) = 0;
                    }
                }
            }
        }
        __syncthreads();

        // ---- S4: grad tile = m1 @ W1y^T ; y -= LR*grad ; refresh y planes
        f32x4 g = (f32x4){0.f, 0.f, 0.f, 0.f};
        const char* bh = (const char*)(wsb + OFF_W1Y4);
        const char* bm = (const char*)(wsb + WS_ELEMS + OFF_W1Y4);
        const char* bl = (const char*)(wsb + 2 * WS_ELEMS + OFF_W1Y4);
        #pragma unroll
        for (int kk = 0; kk < 16; ++kk) {
            const int cb = kk * 64 + l4 * 16;
            const int row = mt4 * 16 + l16;
            const int offA = row * 1024 + (cb ^ ((row & 7) << 4));
            bf16x8 a0  = *(const bf16x8*)(smem + L_A0 + offA);
            bf16x8 a1_ = *(const bf16x8*)(smem + L_A1 + offA);
            bf16x8 a2_ = *(const bf16x8*)(smem + L_A2 + offA);
            const size_t ob = (size_t)(nt4 * 16 + l16) * 1024 + cb;
            bf16x8 b0  = *(const bf16x8*)(bh + ob);
            bf16x8 b1_ = *(const bf16x8*)(bm + ob);
            bf16x8 b2_ = *(const bf16x8*)(bl + ob);
            g = __builtin_amdgcn_mfma_f32_16x16x32_bf16(a0,  b0,  g, 0, 0, 0);
            g = __builtin_amdgcn_mfma_f32_16x16x32_bf16(a0,  b1_, g, 0, 0, 0);
            g = __builtin_amdgcn_mfma_f32_16x16x32_bf16(a1_, b0,  g, 0, 0, 0);
            g = __builtin_amdgcn_mfma_f32_16x16x32_bf16(a0,  b2_, g, 0, 0, 0);
            g = __builtin_amdgcn_mfma_f32_16x16x32_bf16(a2_, b0,  g, 0, 0, 0);
            g = __builtin_amdgcn_mfma_f32_16x16x32_bf16(a1_, b1_, g, 0, 0, 0);
        }
        #pragma unroll
        for (int q = 0; q < 4; ++q) ym[q] = ym[q] - LRC * g[q];
        #pragma unroll
        for (int q = 0; q < 4; ++q) {
            const int row = mt4 * 16 + l4 * 4 + q;
            const int col = nt4 * 16 + l16;
            const int off = row * 128 + ((col * 2) ^ ((row & 7) << 4));
            store3<YPL>(smem + L_Y0, off, ym[q]);
        }
    }

    // write out from fp32 register master
    #pragma unroll
    for (int q = 0; q < 4; ++q) {
        const int row = mt4 * 16 + l4 * 4 + q;
        const int col = nt4 * 16 + l16;
        out[(size_t)(r0 + row) * DYD + col] = ym[q];
    }
}

extern "C" void kernel_launch(void* const* d_in, const int* in_sizes, int n_in,
                              void* d_out, int out_size, void* d_ws, size_t ws_size,
                              hipStream_t stream) {
    const float* x  = (const float*)d_in[0];
    const int*   t  = (const int*)d_in[1];
    const float* W1 = (const float*)d_in[2];
    const float* b1 = (const float*)d_in[3];
    const float* W2 = (const float*)d_in[4];
    const float* b2 = (const float*)d_in[5];
    const float* W3 = (const float*)d_in[6];
    // d_in[7] = b3: constant offset, no effect on grad_y
    const int* steps = (const int*)d_in[8];
    float* out = (float*)d_out;
    unsigned short* wsb = (unsigned short*)d_ws;

    const int B = in_sizes[0] / DXD;
    const int nblocks = B / NROWS;

    wconv<<<(WS_ELEMS + 255) / 256, 256, 0, stream>>>(W1, W2, wsb);

    (void)hipFuncSetAttribute((const void*)ebm_mfma,
                              hipFuncAttributeMaxDynamicSharedMemorySize,
                              SMEM_BYTES);
    ebm_mfma<<<nblocks, NTHR, SMEM_BYTES, stream>>>(x, t, W1, b1, W2, b2, W3, steps, wsb, out);
}

// Round 8
// 47206.577 us; speedup vs baseline: 1.1592x; 1.1592x over previous
//
#include <hip/hip_runtime.h>

typedef short bf16x8 __attribute__((ext_vector_type(8)));
typedef _Float16 f16x8 __attribute__((ext_vector_type(8)));
typedef float f32x4 __attribute__((ext_vector_type(4)));

#define HID   512
#define DXD   256
#define DYD   64
#define NROWS 32
#define NTHR  512
#define LRC   0.1f
#define TAU1  1e-4f
#define TAU2  1e-4f

// ws layout (u16 elements):
// bf16 3-plane group, per-plane span PA: W1YB, W1Y4, W2B; planes at +0,+PA,+2PA
#define OFF_W1YB 0          // [512][64]   W1yB[n][k] = W1[(256+k)*512+n]
#define OFF_W1Y4 32768      // [64][512]   W1y4[d][j] = W1[(256+d)*512+j]
#define OFF_W2B  65536      // [512][512]  W2B[n][k]  = W2[k*512+n]
#define PA       327680
// fp16 2-plane W2B3: [512][512] W2B3[n][k] = W2[n*512+k]
#define F0H      983040     // = 3*PA
#define F0M      1245184    // = F0H + 262144
#define NCONV    589824     // PA + 262144

// LDS layout (bytes)
#define L_A0  0             // act plane hi  [32][512]*2B; x_f32 [32][256]*4B during stage0
#define L_A1  32768         // act plane mid
#define L_A2  65536         // act plane lo
#define APL   32768
#define L_Y0  98304         // y plane hi [32][64]*2B, row stride 128
#define L_Y1  102400
#define L_Y2  106496
#define YPL   4096
#define L_TL  110592
#define SMEM_BYTES 110848

__device__ __forceinline__ unsigned short f2bf(float f) {
    unsigned u = __float_as_uint(f);
    u = (u + 0x7FFFu + ((u >> 16) & 1u)) >> 16;   // RNE
    return (unsigned short)u;
}
__device__ __forceinline__ float bf2f(unsigned short u) {
    return __uint_as_float(((unsigned)u) << 16);
}

template<int PS>
__device__ __forceinline__ void store3(char* base, int off, float v) {
    unsigned short h = f2bf(v);
    float r1 = v - bf2f(h);
    unsigned short m = f2bf(r1);
    float r2 = r1 - bf2f(m);
    *(unsigned short*)(base + off)          = h;
    *(unsigned short*)(base + PS + off)     = m;
    *(unsigned short*)(base + 2 * PS + off) = f2bf(r2);
}

// fp16 2-plane split: v = h + m*2^-12. Values below fp16-normal go entirely
// into the (scaled) m plane so MFMA denormal-flush (if any) costs <=1.5e-8 abs.
__device__ __forceinline__ void f2h2(float v, unsigned short* ph, unsigned short* pm) {
    unsigned short hb, mb;
    if (fabsf(v) >= 6.103515625e-05f) {
        _Float16 h = (_Float16)v;
        _Float16 m = (_Float16)((v - (float)h) * 4096.0f);
        hb = __builtin_bit_cast(unsigned short, h);
        mb = __builtin_bit_cast(unsigned short, m);
    } else {
        _Float16 m = (_Float16)(v * 4096.0f);
        hb = 0;
        mb = __builtin_bit_cast(unsigned short, m);
    }
    *ph = hb; *pm = mb;
}

// 2x4 tile GEMM, 3-plane split-bf16, 6 exact-product terms into ONE fp32 acc.
template<int KSTEPS, int SROWA, int KDIM, int APL_>
__device__ __forceinline__ void gemm6(const char* ldsA, const unsigned short* B,
                                      int l4, int l16, int nt0, f32x4 acc[2][4])
{
    const int cb0 = l4 * 16;
    #pragma unroll
    for (int kk = 0; kk < KSTEPS; ++kk) {
        const int cb = kk * 64 + cb0;
        bf16x8 a0[2], a1_[2], a2_[2], b0[4], b1_[4], b2_[4];
        #pragma unroll
        for (int mt = 0; mt < 2; ++mt) {
            const int row = mt * 16 + l16;
            const int off = row * SROWA + (cb ^ ((row & 7) << 4));
            a0[mt]  = *(const bf16x8*)(ldsA + off);
            a1_[mt] = *(const bf16x8*)(ldsA + APL_ + off);
            a2_[mt] = *(const bf16x8*)(ldsA + 2 * APL_ + off);
        }
        #pragma unroll
        for (int nq = 0; nq < 4; ++nq) {
            const size_t off = (size_t)((nt0 + nq) * 16 + l16) * (KDIM * 2) + cb;
            b0[nq]  = *(const bf16x8*)((const char*)B + off);
            b1_[nq] = *(const bf16x8*)((const char*)(B + PA) + off);
            b2_[nq] = *(const bf16x8*)((const char*)(B + 2 * PA) + off);
        }
        #pragma unroll
        for (int mt = 0; mt < 2; ++mt)
            #pragma unroll
            for (int nq = 0; nq < 4; ++nq) {
                acc[mt][nq] = __builtin_amdgcn_mfma_f32_16x16x32_bf16(a0[mt],  b0[nq],  acc[mt][nq], 0, 0, 0);
                acc[mt][nq] = __builtin_amdgcn_mfma_f32_16x16x32_bf16(a0[mt],  b1_[nq], acc[mt][nq], 0, 0, 0);
                acc[mt][nq] = __builtin_amdgcn_mfma_f32_16x16x32_bf16(a1_[mt], b0[nq],  acc[mt][nq], 0, 0, 0);
                acc[mt][nq] = __builtin_amdgcn_mfma_f32_16x16x32_bf16(a0[mt],  b2_[nq], acc[mt][nq], 0, 0, 0);
                acc[mt][nq] = __builtin_amdgcn_mfma_f32_16x16x32_bf16(a2_[mt], b0[nq],  acc[mt][nq], 0, 0, 0);
                acc[mt][nq] = __builtin_amdgcn_mfma_f32_16x16x32_bf16(a1_[mt], b1_[nq], acc[mt][nq], 0, 0, 0);
            }
    }
}

// 2x4 tile GEMM, fp16 2-plane (A in LDS planes 0/1; B = W2B3 fp16 tables).
// acc += Ah*Bh + (Ah*Bm + Am*Bh)*2^-12  (second accumulator carries the 2^12 scale)
template<int KSTEPS, int SROWA, int KDIM, int APL_>
__device__ __forceinline__ void gemm3h(const char* ldsA, const unsigned short* Bh,
                                       const unsigned short* Bm,
                                       int l4, int l16, int nt0, f32x4 acc[2][4])
{
    f32x4 accm[2][4];
    #pragma unroll
    for (int mt = 0; mt < 2; ++mt)
        #pragma unroll
        for (int nq = 0; nq < 4; ++nq)
            accm[mt][nq] = (f32x4){0.f, 0.f, 0.f, 0.f};
    const int cb0 = l4 * 16;
    #pragma unroll
    for (int kk = 0; kk < KSTEPS; ++kk) {
        const int cb = kk * 64 + cb0;
        f16x8 ah[2], am[2], bh[4], bm[4];
        #pragma unroll
        for (int mt = 0; mt < 2; ++mt) {
            const int row = mt * 16 + l16;
            const int off = row * SROWA + (cb ^ ((row & 7) << 4));
            ah[mt] = *(const f16x8*)(ldsA + off);
            am[mt] = *(const f16x8*)(ldsA + APL_ + off);
        }
        #pragma unroll
        for (int nq = 0; nq < 4; ++nq) {
            const size_t off = (size_t)((nt0 + nq) * 16 + l16) * (KDIM * 2) + cb;
            bh[nq] = *(const f16x8*)((const char*)Bh + off);
            bm[nq] = *(const f16x8*)((const char*)Bm + off);
        }
        #pragma unroll
        for (int mt = 0; mt < 2; ++mt)
            #pragma unroll
            for (int nq = 0; nq < 4; ++nq) {
                acc[mt][nq]  = __builtin_amdgcn_mfma_f32_16x16x32_f16(ah[mt], bh[nq], acc[mt][nq],  0, 0, 0);
                accm[mt][nq] = __builtin_amdgcn_mfma_f32_16x16x32_f16(ah[mt], bm[nq], accm[mt][nq], 0, 0, 0);
                accm[mt][nq] = __builtin_amdgcn_mfma_f32_16x16x32_f16(am[mt], bh[nq], accm[mt][nq], 0, 0, 0);
            }
    }
    #pragma unroll
    for (int mt = 0; mt < 2; ++mt)
        #pragma unroll
        for (int nq = 0; nq < 4; ++nq)
            #pragma unroll
            for (int q = 0; q < 4; ++q)
                acc[mt][nq][q] += accm[mt][nq][q] * 2.44140625e-4f;
}

// Serial fp32 recompute of a2[row][col]; W2 column reconstructed from the
// (L2-hot, contiguous) W2B bf16-3 table row `col`.
__device__ __attribute__((noinline))
float rescue_s2(const char* smem, int row, int col, float b2n,
                const unsigned short* __restrict__ wsb) {
    float r = b2n;
    const int xr = (row & 7) << 4;
    const int rb = row * 1024;
    const bf16x8* w0 = (const bf16x8*)(wsb + OFF_W2B + (size_t)col * 512);
    const bf16x8* w1 = (const bf16x8*)(wsb + PA + OFF_W2B + (size_t)col * 512);
    const bf16x8* w2p = (const bf16x8*)(wsb + 2 * PA + OFF_W2B + (size_t)col * 512);
    for (int j0 = 0; j0 < HID; j0 += 8) {
        const int off = rb + ((j0 * 2) ^ xr);
        bf16x8 h  = *(const bf16x8*)(smem + L_A0 + off);
        bf16x8 m_ = *(const bf16x8*)(smem + L_A1 + off);
        bf16x8 l  = *(const bf16x8*)(smem + L_A2 + off);
        bf16x8 wh = w0[j0 >> 3], wm = w1[j0 >> 3], wl = w2p[j0 >> 3];
        #pragma unroll
        for (int u = 0; u < 8; ++u) {
            float hv = (bf2f((unsigned short)h[u]) + bf2f((unsigned short)m_[u])) + bf2f((unsigned short)l[u]);
            float wv = (bf2f((unsigned short)wh[u]) + bf2f((unsigned short)wm[u])) + bf2f((unsigned short)wl[u]);
            r = fmaf(hv, wv, r);
        }
    }
    return r;
}

// Serial fp32 recompute of a1[row][col]; W1y column from the W1YB table row `col`.
__device__ __attribute__((noinline))
float rescue_s1(const char* smem, int row, int col, float cval,
                const unsigned short* __restrict__ wsb) {
    float r = cval;
    const int xr = (row & 7) << 4;
    const int rb = row * 128;
    const bf16x8* w0 = (const bf16x8*)(wsb + OFF_W1YB + (size_t)col * 64);
    const bf16x8* w1 = (const bf16x8*)(wsb + PA + OFF_W1YB + (size_t)col * 64);
    const bf16x8* w2p = (const bf16x8*)(wsb + 2 * PA + OFF_W1YB + (size_t)col * 64);
    for (int j0 = 0; j0 < DYD; j0 += 8) {
        const int off = rb + ((j0 * 2) ^ xr);
        bf16x8 h  = *(const bf16x8*)(smem + L_Y0 + off);
        bf16x8 m_ = *(const bf16x8*)(smem + L_Y1 + off);
        bf16x8 l  = *(const bf16x8*)(smem + L_Y2 + off);
        bf16x8 wh = w0[j0 >> 3], wm = w1[j0 >> 3], wl = w2p[j0 >> 3];
        #pragma unroll
        for (int u = 0; u < 8; ++u) {
            float yv = (bf2f((unsigned short)h[u]) + bf2f((unsigned short)m_[u])) + bf2f((unsigned short)l[u]);
            float wv = (bf2f((unsigned short)wh[u]) + bf2f((unsigned short)wm[u])) + bf2f((unsigned short)wl[u]);
            r = fmaf(yv, wv, r);
        }
    }
    return r;
}

__global__ void wconv(const float* __restrict__ W1, const float* __restrict__ W2,
                      unsigned short* __restrict__ wsb)
{
    int i = blockIdx.x * blockDim.x + threadIdx.x;
    if (i >= NCONV) return;
    if (i < PA) {
        float v;
        if (i < OFF_W1Y4)      { int n = i >> 6, k = i & 63;                 v = W1[(256 + k) * 512 + n]; }
        else if (i < OFF_W2B)  { int j = i - OFF_W1Y4, d = j >> 9, k = j & 511; v = W1[(256 + d) * 512 + k]; }
        else                   { int j = i - OFF_W2B,  n = j >> 9, k = j & 511; v = W2[k * 512 + n]; }
        unsigned short h = f2bf(v);
        float r1 = v - bf2f(h);
        unsigned short m = f2bf(r1);
        float r2 = r1 - bf2f(m);
        wsb[i]          = h;
        wsb[i + PA]     = m;
        wsb[i + 2 * PA] = f2bf(r2);
    } else {
        int j = i - PA;
        int n = j >> 9, k = j & 511;
        float v = W2[n * 512 + k];             // W2B3[n][k] = W2^T column layout
        f2h2(v, &wsb[F0H + j], &wsb[F0M + j]);
    }
}

__global__ __launch_bounds__(NTHR, 2)
void ebm_mfma(const float* __restrict__ x, const int* __restrict__ tt,
              const float* __restrict__ W1, const float* __restrict__ b1,
              const float* __restrict__ W2, const float* __restrict__ b2,
              const float* __restrict__ W3, const int* __restrict__ stepsp,
              const unsigned short* __restrict__ wsb, float* __restrict__ out)
{
    extern __shared__ char smem[];

    const int tid  = threadIdx.x;
    const int w    = tid >> 6, lane = tid & 63;
    const int l4   = lane >> 4, l16 = lane & 15;
    const int r0   = blockIdx.x * NROWS;
    const int nt0  = w * 4;
    const int nsteps = *stepsp;

    if (tid < NROWS) {
        int tv = tt[r0 + tid];
        ((int*)(smem + L_TL))[tid] = tv < 0 ? 0 : tv;
    }
    for (int i = tid; i < 3 * YPL / 4; i += NTHR) ((unsigned*)(smem + L_Y0))[i] = 0u;

    // stage x -> fp32 [32][256] (row stride 1024B) in plane0 region (used only by stage0)
    {
        const float4* xg = (const float4*)(x + (size_t)r0 * DXD);
        #pragma unroll
        for (int j = 0; j < 4; ++j) {
            int i4 = j * NTHR + tid;
            ((float4*)(smem + L_A0))[i4] = xg[i4];
        }
    }
    __syncthreads();

    // ---- stage 0: c = x @ W1x + b1 in EXACT fp32 VALU
    f32x4 c_reg[2][4];
    {
        float bb[4];
        #pragma unroll
        for (int nq = 0; nq < 4; ++nq) bb[nq] = b1[(nt0 + nq) * 16 + l16];
        #pragma unroll
        for (int mt = 0; mt < 2; ++mt)
            #pragma unroll
            for (int nq = 0; nq < 4; ++nq)
                c_reg[mt][nq] = (f32x4){bb[nq], bb[nq], bb[nq], bb[nq]};
        for (int i = 0; i < DXD; i += 4) {
            float wv[4][4];
            #pragma unroll
            for (int d = 0; d < 4; ++d)
                #pragma unroll
                for (int nq = 0; nq < 4; ++nq)
                    wv[d][nq] = W1[(size_t)(i + d) * HID + (nt0 + nq) * 16 + l16];
            #pragma unroll
            for (int mt = 0; mt < 2; ++mt)
                #pragma unroll
                for (int q = 0; q < 4; ++q) {
                    const int row = mt * 16 + l4 * 4 + q;
                    float4 xv = *(const float4*)(smem + L_A0 + row * 1024 + i * 4);
                    #pragma unroll
                    for (int nq = 0; nq < 4; ++nq) {
                        c_reg[mt][nq][q] = fmaf(xv.x, wv[0][nq], c_reg[mt][nq][q]);
                        c_reg[mt][nq][q] = fmaf(xv.y, wv[1][nq], c_reg[mt][nq][q]);
                        c_reg[mt][nq][q] = fmaf(xv.z, wv[2][nq], c_reg[mt][nq][q]);
                        c_reg[mt][nq][q] = fmaf(xv.w, wv[3][nq], c_reg[mt][nq][q]);
                    }
                }
        }
    }

    float b2v[4];
    #pragma unroll
    for (int nq = 0; nq < 4; ++nq) b2v[nq] = b2[(nt0 + nq) * 16 + l16];

    const int mt4 = w & 1;
    const int nt4 = w >> 1;
    f32x4 ym = (f32x4){0.f, 0.f, 0.f, 0.f};

    for (int s = 0; s < nsteps; ++s) {
        __syncthreads();

        // ---- S1: a1 = c + y @ W1y ; rescue ties ; h1 = relu -> bf16-3 planes
        f32x4 acc[2][4];
        #pragma unroll
        for (int mt = 0; mt < 2; ++mt)
            #pragma unroll
            for (int nq = 0; nq < 4; ++nq)
                acc[mt][nq] = c_reg[mt][nq];
        gemm6<2, 128, 64, YPL>(smem + L_Y0, wsb + OFF_W1YB, l4, l16, nt0, acc);

        unsigned mk = 0u;
        #pragma unroll
        for (int mt = 0; mt < 2; ++mt) {
            #pragma unroll
            for (int nq = 0; nq < 4; ++nq) {
                const int col = (nt0 + nq) * 16 + l16;
                #pragma unroll
                for (int q = 0; q < 4; ++q) {
                    const int row = mt * 16 + l4 * 4 + q;
                    float v = acc[mt][nq][q];
                    if (fabsf(v) < TAU1)
                        v = rescue_s1(smem, row, col, c_reg[mt][nq][q], wsb);
                    const int off = row * 1024 + ((col * 2) ^ ((row & 7) << 4));
                    if (v > 0.f) {
                        mk |= 1u << ((mt * 4 + nq) * 4 + q);
                        store3<APL>(smem + L_A0, off, v);
                    } else {
                        *(unsigned short*)(smem + L_A0 + off) = 0;
                        *(unsigned short*)(smem + L_A1 + off) = 0;
                        *(unsigned short*)(smem + L_A2 + off) = 0;
                    }
                }
            }
        }
        __syncthreads();

        // ---- S2: a2 = h1 @ W2 + b2 ; rescue ties
        #pragma unroll
        for (int mt = 0; mt < 2; ++mt)
            #pragma unroll
            for (int nq = 0; nq < 4; ++nq)
                acc[mt][nq] = (f32x4){b2v[nq], b2v[nq], b2v[nq], b2v[nq]};
        gemm6<16, 1024, 512, APL>(smem + L_A0, wsb + OFF_W2B, l4, l16, nt0, acc);

        unsigned pos2 = 0u;
        #pragma unroll
        for (int mt = 0; mt < 2; ++mt) {
            #pragma unroll
            for (int nq = 0; nq < 4; ++nq) {
                const int col = (nt0 + nq) * 16 + l16;
                #pragma unroll
                for (int q = 0; q < 4; ++q) {
                    const int row = mt * 16 + l4 * 4 + q;
                    float v = acc[mt][nq][q];
                    if (fabsf(v) < TAU2)
                        v = rescue_s2(smem, row, col, b2v[nq], wsb);
                    if (v > 0.f) pos2 |= 1u << ((mt * 4 + nq) * 4 + q);
                }
            }
        }
        __syncthreads();   // all h1 reads (gemm + rescue) done

        // S2 epi: m2 = pos ? W3[col][t_row] : 0 -> fp16-2 planes (A0/A1)
        #pragma unroll
        for (int mt = 0; mt < 2; ++mt) {
            #pragma unroll
            for (int nq = 0; nq < 4; ++nq) {
                const int col = (nt0 + nq) * 16 + l16;
                #pragma unroll
                for (int q = 0; q < 4; ++q) {
                    const int row = mt * 16 + l4 * 4 + q;
                    const int tv = ((const int*)(smem + L_TL))[row];
                    const int off = row * 1024 + ((col * 2) ^ ((row & 7) << 4));
                    if ((pos2 >> ((mt * 4 + nq) * 4 + q)) & 1u) {
                        f2h2(W3[col * 4 + tv],
                             (unsigned short*)(smem + L_A0 + off),
                             (unsigned short*)(smem + L_A1 + off));
                    } else {
                        *(unsigned short*)(smem + L_A0 + off) = 0;
                        *(unsigned short*)(smem + L_A1 + off) = 0;
                    }
                }
            }
        }
        __syncthreads();

        // ---- S3: g2 = m2 @ W2^T  (fp16 2-plane; no sign decisions here)
        #pragma unroll
        for (int mt = 0; mt < 2; ++mt)
            #pragma unroll
            for (int nq = 0; nq < 4; ++nq)
                acc[mt][nq] = (f32x4){0.f, 0.f, 0.f, 0.f};
        gemm3h<16, 1024, 512, APL>(smem + L_A0, wsb + F0H, wsb + F0M, l4, l16, nt0, acc);
        __syncthreads();   // all m2 reads done

        // S3 epi: m1 = mask1 ? g2 : 0 -> bf16-3 planes
        #pragma unroll
        for (int mt = 0; mt < 2; ++mt) {
            #pragma unroll
            for (int nq = 0; nq < 4; ++nq) {
                const int col2 = ((nt0 + nq) * 16 + l16) * 2;
                #pragma unroll
                for (int q = 0; q < 4; ++q) {
                    const int row = mt * 16 + l4 * 4 + q;
                    const int off = row * 1024 + (col2 ^ ((row & 7) << 4));
                    if ((mk >> ((mt * 4 + nq) * 4 + q)) & 1u) {
                        store3<APL>(smem + L_A0, off, acc[mt][nq][q]);
                    } else {
                        *(unsigned short*)(smem + L_A0 + off) = 0;
                        *(unsigned short*)(smem + L_A1 + off) = 0;
                        *(unsigned short*)(smem + L_A2 + off) = 0;
                    }
                }
            }
        }
        __syncthreads();

        // ---- S4: grad tile = m1 @ W1y^T ; y -= LR*grad ; refresh y planes
        f32x4 g = (f32x4){0.f, 0.f, 0.f, 0.f};
        const char* bh = (const char*)(wsb + OFF_W1Y4);
        const char* bm = (const char*)(wsb + PA + OFF_W1Y4);
        const char* bl = (const char*)(wsb + 2 * PA + OFF_W1Y4);
        #pragma unroll
        for (int kk = 0; kk < 16; ++kk) {
            const int cb = kk * 64 + l4 * 16;
            const int row = mt4 * 16 + l16;
            const int offA = row * 1024 + (cb ^ ((row & 7) << 4));
            bf16x8 a0  = *(const bf16x8*)(smem + L_A0 + offA);
            bf16x8 a1_ = *(const bf16x8*)(smem + L_A1 + offA);
            bf16x8 a2_ = *(const bf16x8*)(smem + L_A2 + offA);
            const size_t ob = (size_t)(nt4 * 16 + l16) * 1024 + cb;
            bf16x8 b0  = *(const bf16x8*)(bh + ob);
            bf16x8 b1_ = *(const bf16x8*)(bm + ob);
            bf16x8 b2_ = *(const bf16x8*)(bl + ob);
            g = __builtin_amdgcn_mfma_f32_16x16x32_bf16(a0,  b0,  g, 0, 0, 0);
            g = __builtin_amdgcn_mfma_f32_16x16x32_bf16(a0,  b1_, g, 0, 0, 0);
            g = __builtin_amdgcn_mfma_f32_16x16x32_bf16(a1_, b0,  g, 0, 0, 0);
            g = __builtin_amdgcn_mfma_f32_16x16x32_bf16(a0,  b2_, g, 0, 0, 0);
            g = __builtin_amdgcn_mfma_f32_16x16x32_bf16(a2_, b0,  g, 0, 0, 0);
            g = __builtin_amdgcn_mfma_f32_16x16x32_bf16(a1_, b1_, g, 0, 0, 0);
        }
        #pragma unroll
        for (int q = 0; q < 4; ++q) ym[q] = ym[q] - LRC * g[q];
        #pragma unroll
        for (int q = 0; q < 4; ++q) {
            const int row = mt4 * 16 + l4 * 4 + q;
            const int col = nt4 * 16 + l16;
            const int off = row * 128 + ((col * 2) ^ ((row & 7) << 4));
            store3<YPL>(smem + L_Y0, off, ym[q]);
        }
    }

    // write out from fp32 register master
    #pragma unroll
    for (int q = 0; q < 4; ++q) {
        const int row = mt4 * 16 + l4 * 4 + q;
        const int col = nt4 * 16 + l16;
        out[(size_t)(r0 + row) * DYD + col] = ym[q];
    }
}

extern "C" void kernel_launch(void* const* d_in, const int* in_sizes, int n_in,
                              void* d_out, int out_size, void* d_ws, size_t ws_size,
                              hipStream_t stream) {
    const float* x  = (const float*)d_in[0];
    const int*   t  = (const int*)d_in[1];
    const float* W1 = (const float*)d_in[2];
    const float* b1 = (const float*)d_in[3];
    const float* W2 = (const float*)d_in[4];
    const float* b2 = (const float*)d_in[5];
    const float* W3 = (const float*)d_in[6];
    // d_in[7] = b3: constant offset, no effect on grad_y
    const int* steps = (const int*)d_in[8];
    float* out = (float*)d_out;
    unsigned short* wsb = (unsigned short*)d_ws;

    const int B = in_sizes[0] / DXD;
    const int nblocks = B / NROWS;

    wconv<<<(NCONV + 255) / 256, 256, 0, stream>>>(W1, W2, wsb);

    (void)hipFuncSetAttribute((const void*)ebm_mfma,
                              hipFuncAttributeMaxDynamicSharedMemorySize,
                              SMEM_BYTES);
    ebm_mfma<<<nblocks, NTHR, SMEM_BYTES, stream>>>(x, t, W1, b1, W2, b2, W3, steps, wsb, out);
}

// Round 9
// 34920.911 us; speedup vs baseline: 1.5671x; 1.3518x over previous
//
#include <hip/hip_runtime.h>

typedef _Float16 f16x8 __attribute__((ext_vector_type(8)));
typedef float f32x4 __attribute__((ext_vector_type(4)));

#define HID   512
#define DXD   256
#define DYD   64
#define NROWS 64
#define NTHR  512
#define LRC   0.1f
#define TAU1  1e-4f
#define TAU2  1e-4f
#define SC12  2.44140625e-4f   // 2^-12

// ws layout (u16 elements), all fp16 2-plane: h at +0, m(x4096) at +PH
#define OFF_W1YB 0          // [512][64]   W1yB[n][k] = W1[(256+k)*512+n]
#define OFF_W1Y4 32768      // [64][512]   W1y4[d][j] = W1[(256+d)*512+j]
#define OFF_W2B  65536      // [512][512]  W2B[n][k]  = W2[k*512+n]
#define OFF_W2B3 327680     // [512][512]  W2B3[n][k] = W2[n*512+k]
#define PH       589824

// LDS layout (bytes)
#define L_H0  0             // act plane h [64][512]*2B row stride 1024; x_f32 [64][256]*4B during stage0
#define L_H1  65536         // act plane m
#define HPL   65536
#define L_Y0  131072        // y plane h [64][64]*2B row stride 128
#define L_Y1  139264        // y plane m
#define YPL   8192
#define L_TL  147456        // 64 ints
#define SMEM_BYTES 147712

// fp16 2-plane split: v = h + m*2^-12 (m scaled x4096 to stay normal).
__device__ __forceinline__ void f2h2(float v, unsigned short* ph, unsigned short* pm) {
    unsigned short hb, mb;
    if (fabsf(v) >= 6.103515625e-05f) {
        _Float16 h = (_Float16)v;
        _Float16 m = (_Float16)((v - (float)h) * 4096.0f);
        hb = __builtin_bit_cast(unsigned short, h);
        mb = __builtin_bit_cast(unsigned short, m);
    } else {
        _Float16 m = (_Float16)(v * 4096.0f);
        hb = 0;
        mb = __builtin_bit_cast(unsigned short, m);
    }
    *ph = hb; *pm = mb;
}
__device__ __forceinline__ float h2f2(unsigned short h, unsigned short m) {
    return (float)__builtin_bit_cast(_Float16, h) +
           (float)__builtin_bit_cast(_Float16, m) * SC12;
}

// 4mt x 2nq tile GEMM, fp16 2-plane, 3 exact-product terms.
// acc += Ah*Bh ; accm += Ah*Bm + Am*Bh  (caller folds accm*2^-12)
template<int KSTEPS, int SROWA, int KDIM, int APL_>
__device__ __forceinline__ void gemmh(const char* ldsA, const unsigned short* B,
                                      int l4, int l16, int ct,
                                      f32x4 acc[4][2], f32x4 accm[4][2])
{
    const int cb0 = l4 * 16;
    #pragma unroll
    for (int kk = 0; kk < KSTEPS; ++kk) {
        const int cb = kk * 64 + cb0;
        f16x8 ah[4], am[4], bh[2], bm[2];
        #pragma unroll
        for (int mt = 0; mt < 4; ++mt) {
            const int row = mt * 16 + l16;
            const int off = row * SROWA + (cb ^ ((row & 7) << 4));
            ah[mt] = *(const f16x8*)(ldsA + off);
            am[mt] = *(const f16x8*)(ldsA + APL_ + off);
        }
        #pragma unroll
        for (int nq = 0; nq < 2; ++nq) {
            const size_t off = (size_t)((ct + nq) * 16 + l16) * (KDIM * 2) + cb;
            bh[nq] = *(const f16x8*)((const char*)B + off);
            bm[nq] = *(const f16x8*)((const char*)(B + PH) + off);
        }
        #pragma unroll
        for (int mt = 0; mt < 4; ++mt)
            #pragma unroll
            for (int nq = 0; nq < 2; ++nq) {
                acc[mt][nq]  = __builtin_amdgcn_mfma_f32_16x16x32_f16(ah[mt], bh[nq], acc[mt][nq],  0, 0, 0);
                accm[mt][nq] = __builtin_amdgcn_mfma_f32_16x16x32_f16(ah[mt], bm[nq], accm[mt][nq], 0, 0, 0);
                accm[mt][nq] = __builtin_amdgcn_mfma_f32_16x16x32_f16(am[mt], bh[nq], accm[mt][nq], 0, 0, 0);
            }
    }
}

// Serial fp32 recompute of a2[row][col] from fp16-2 LDS h1 + fp16-2 W2B row `col`.
__device__ __attribute__((noinline))
float rescue_s2(const char* smem, int row, int col, float b2n,
                const unsigned short* __restrict__ wsb) {
    float r = b2n;
    const int xr = (row & 7) << 4;
    const int rb = row * 1024;
    const char* wh = (const char*)(wsb + OFF_W2B) + (size_t)col * 1024;
    const char* wm = (const char*)(wsb + PH + OFF_W2B) + (size_t)col * 1024;
    for (int j0 = 0; j0 < HID; j0 += 8) {
        const int off = rb + ((j0 * 2) ^ xr);
        f16x8 h  = *(const f16x8*)(smem + L_H0 + off);
        f16x8 m_ = *(const f16x8*)(smem + L_H1 + off);
        f16x8 bh = *(const f16x8*)(wh + j0 * 2);
        f16x8 bm = *(const f16x8*)(wm + j0 * 2);
        #pragma unroll
        for (int u = 0; u < 8; ++u) {
            float hv = (float)h[u]  + (float)m_[u] * SC12;
            float wv = (float)bh[u] + (float)bm[u] * SC12;
            r = fmaf(hv, wv, r);
        }
    }
    return r;
}

// Serial fp32 recompute of a1[row][col] from exact c and fp16-2 LDS y + W1YB row `col`.
__device__ __attribute__((noinline))
float rescue_s1(const char* smem, int row, int col, float cval,
                const unsigned short* __restrict__ wsb) {
    float r = cval;
    const int xr = (row & 7) << 4;
    const int rb = row * 128;
    const char* wh = (const char*)(wsb + OFF_W1YB) + (size_t)col * 128;
    const char* wm = (const char*)(wsb + PH + OFF_W1YB) + (size_t)col * 128;
    for (int j0 = 0; j0 < DYD; j0 += 8) {
        const int off = rb + ((j0 * 2) ^ xr);
        f16x8 h  = *(const f16x8*)(smem + L_Y0 + off);
        f16x8 m_ = *(const f16x8*)(smem + L_Y1 + off);
        f16x8 bh = *(const f16x8*)(wh + j0 * 2);
        f16x8 bm = *(const f16x8*)(wm + j0 * 2);
        #pragma unroll
        for (int u = 0; u < 8; ++u) {
            float yv = (float)h[u]  + (float)m_[u] * SC12;
            float wv = (float)bh[u] + (float)bm[u] * SC12;
            r = fmaf(yv, wv, r);
        }
    }
    return r;
}

__global__ void wconv(const float* __restrict__ W1, const float* __restrict__ W2,
                      unsigned short* __restrict__ wsb)
{
    int i = blockIdx.x * blockDim.x + threadIdx.x;
    if (i >= PH) return;
    float v;
    if (i < OFF_W1Y4)      { int n = i >> 6, k = i & 63;                    v = W1[(256 + k) * 512 + n]; }
    else if (i < OFF_W2B)  { int j = i - OFF_W1Y4, d = j >> 9, k = j & 511; v = W1[(256 + d) * 512 + k]; }
    else if (i < OFF_W2B3) { int j = i - OFF_W2B,  n = j >> 9, k = j & 511; v = W2[k * 512 + n]; }
    else                   { int j = i - OFF_W2B3, n = j >> 9, k = j & 511; v = W2[n * 512 + k]; }
    f2h2(v, &wsb[i], &wsb[i + PH]);
}

__global__ __launch_bounds__(NTHR, 2)
void ebm_mfma(const float* __restrict__ x, const int* __restrict__ tt,
              const float* __restrict__ W1, const float* __restrict__ b1,
              const float* __restrict__ W2, const float* __restrict__ b2,
              const float* __restrict__ W3, const int* __restrict__ stepsp,
              const unsigned short* __restrict__ wsb, float* __restrict__ out)
{
    extern __shared__ char smem[];

    const int tid  = threadIdx.x;
    const int w    = tid >> 6, lane = tid & 63;
    const int l4   = lane >> 4, l16 = lane & 15;
    const int r0   = blockIdx.x * NROWS;
    const int nt0  = w * 4;          // wave's 4 16-col tiles (64 cols)
    const int nsteps = *stepsp;

    if (tid < NROWS) {
        int tv = tt[r0 + tid];
        ((int*)(smem + L_TL))[tid] = tv < 0 ? 0 : tv;
    }
    // zero y planes (2 * 8KB)
    for (int i = tid; i < 2 * YPL / 4; i += NTHR) ((unsigned*)(smem + L_Y0))[i] = 0u;

    // stage x -> fp32 [64][256] (row stride 1024B) in L_H0/L_H1 region
    {
        const float4* xg = (const float4*)(x + (size_t)r0 * DXD);
        #pragma unroll
        for (int j = 0; j < 8; ++j) {
            int i4 = j * NTHR + tid;          // 4096 float4 = 64 rows * 64
            ((float4*)(smem + L_H0))[i4] = xg[i4];
        }
    }
    __syncthreads();

    // ---- stage 0: c = x @ W1x + b1, EXACT fp32 VALU (r6-identical chain per element)
    f32x4 c_reg[4][4];
    {
        float bb[4];
        #pragma unroll
        for (int nq = 0; nq < 4; ++nq) bb[nq] = b1[(nt0 + nq) * 16 + l16];
        #pragma unroll
        for (int mt = 0; mt < 4; ++mt)
            #pragma unroll
            for (int nq = 0; nq < 4; ++nq)
                c_reg[mt][nq] = (f32x4){bb[nq], bb[nq], bb[nq], bb[nq]};
        for (int i = 0; i < DXD; i += 4) {
            float wv[4][4];
            #pragma unroll
            for (int d = 0; d < 4; ++d)
                #pragma unroll
                for (int nq = 0; nq < 4; ++nq)
                    wv[d][nq] = W1[(size_t)(i + d) * HID + (nt0 + nq) * 16 + l16];
            #pragma unroll
            for (int mt = 0; mt < 4; ++mt)
                #pragma unroll
                for (int q = 0; q < 4; ++q) {
                    const int row = mt * 16 + l4 * 4 + q;
                    float4 xv = *(const float4*)(smem + L_H0 + row * 1024 + i * 4);
                    #pragma unroll
                    for (int nq = 0; nq < 4; ++nq) {
                        c_reg[mt][nq][q] = fmaf(xv.x, wv[0][nq], c_reg[mt][nq][q]);
                        c_reg[mt][nq][q] = fmaf(xv.y, wv[1][nq], c_reg[mt][nq][q]);
                        c_reg[mt][nq][q] = fmaf(xv.z, wv[2][nq], c_reg[mt][nq][q]);
                        c_reg[mt][nq][q] = fmaf(xv.w, wv[3][nq], c_reg[mt][nq][q]);
                    }
                }
        }
    }

    float b2v[4];
    #pragma unroll
    for (int nq = 0; nq < 4; ++nq) b2v[nq] = b2[(nt0 + nq) * 16 + l16];

    // S4 tiles: rows mt4*16.., cols ntA/ntB *16..
    const int mt4 = w >> 1;
    const int ntA = (w & 1) * 2;
    const int ntB = ntA + 1;
    f32x4 ymA = (f32x4){0.f, 0.f, 0.f, 0.f};
    f32x4 ymB = (f32x4){0.f, 0.f, 0.f, 0.f};

    for (int s = 0; s < nsteps; ++s) {
        __syncthreads();   // prev S4 act reads + y writes done

        // ---- S1: a1 = c + y @ W1y ; rescue ties ; h1 = relu -> fp16-2 planes
        unsigned long long mk = 0ull;
        #pragma unroll
        for (int half = 0; half < 2; ++half) {
            f32x4 acc[4][2], accm[4][2];
            #pragma unroll
            for (int mt = 0; mt < 4; ++mt)
                #pragma unroll
                for (int nq = 0; nq < 2; ++nq) {
                    acc[mt][nq]  = c_reg[mt][half * 2 + nq];
                    accm[mt][nq] = (f32x4){0.f, 0.f, 0.f, 0.f};
                }
            gemmh<2, 128, 64, YPL>(smem + L_Y0, wsb + OFF_W1YB, l4, l16, nt0 + half * 2, acc, accm);
            #pragma unroll
            for (int mt = 0; mt < 4; ++mt) {
                #pragma unroll
                for (int nq = 0; nq < 2; ++nq) {
                    const int nqg = half * 2 + nq;
                    const int col = (nt0 + nqg) * 16 + l16;
                    #pragma unroll
                    for (int q = 0; q < 4; ++q) {
                        const int row = mt * 16 + l4 * 4 + q;
                        float v = acc[mt][nq][q] + accm[mt][nq][q] * SC12;
                        if (fabsf(v) < TAU1)
                            v = rescue_s1(smem, row, col, c_reg[mt][nqg][q], wsb);
                        const int off = row * 1024 + ((col * 2) ^ ((row & 7) << 4));
                        if (v > 0.f) {
                            mk |= 1ull << ((mt * 4 + nqg) * 4 + q);
                            f2h2(v, (unsigned short*)(smem + L_H0 + off),
                                    (unsigned short*)(smem + L_H1 + off));
                        } else {
                            *(unsigned short*)(smem + L_H0 + off) = 0;
                            *(unsigned short*)(smem + L_H1 + off) = 0;
                        }
                    }
                }
            }
        }
        __syncthreads();

        // ---- S2: a2 = h1 @ W2 + b2 ; rescue ties -> pos2 bits
        unsigned long long pos2 = 0ull;
        #pragma unroll
        for (int half = 0; half < 2; ++half) {
            f32x4 acc[4][2], accm[4][2];
            #pragma unroll
            for (int mt = 0; mt < 4; ++mt)
                #pragma unroll
                for (int nq = 0; nq < 2; ++nq) {
                    const float bb = b2v[half * 2 + nq];
                    acc[mt][nq]  = (f32x4){bb, bb, bb, bb};
                    accm[mt][nq] = (f32x4){0.f, 0.f, 0.f, 0.f};
                }
            gemmh<16, 1024, 512, HPL>(smem + L_H0, wsb + OFF_W2B, l4, l16, nt0 + half * 2, acc, accm);
            #pragma unroll
            for (int mt = 0; mt < 4; ++mt) {
                #pragma unroll
                for (int nq = 0; nq < 2; ++nq) {
                    const int nqg = half * 2 + nq;
                    const int col = (nt0 + nqg) * 16 + l16;
                    #pragma unroll
                    for (int q = 0; q < 4; ++q) {
                        const int row = mt * 16 + l4 * 4 + q;
                        float v = acc[mt][nq][q] + accm[mt][nq][q] * SC12;
                        if (fabsf(v) < TAU2)
                            v = rescue_s2(smem, row, col, b2v[nqg], wsb);
                        if (v > 0.f) pos2 |= 1ull << ((mt * 4 + nqg) * 4 + q);
                    }
                }
            }
        }
        __syncthreads();   // all h1 reads (gemm + rescue) done

        // S2 epi: m2 = pos ? W3[col][t_row] : 0 -> fp16-2 planes (exact gather)
        #pragma unroll
        for (int mt = 0; mt < 4; ++mt) {
            #pragma unroll
            for (int nq = 0; nq < 4; ++nq) {
                const int col = (nt0 + nq) * 16 + l16;
                #pragma unroll
                for (int q = 0; q < 4; ++q) {
                    const int row = mt * 16 + l4 * 4 + q;
                    const int tv = ((const int*)(smem + L_TL))[row];
                    const int off = row * 1024 + ((col * 2) ^ ((row & 7) << 4));
                    if ((pos2 >> ((mt * 4 + nq) * 4 + q)) & 1ull) {
                        f2h2(W3[col * 4 + tv],
                             (unsigned short*)(smem + L_H0 + off),
                             (unsigned short*)(smem + L_H1 + off));
                    } else {
                        *(unsigned short*)(smem + L_H0 + off) = 0;
                        *(unsigned short*)(smem + L_H1 + off) = 0;
                    }
                }
            }
        }
        __syncthreads();

        // ---- S3: g2 = m2 @ W2^T ; m1 = mask1 ? g2 : 0 -> fp16-2 planes
        f32x4 g2v[4][4];
        #pragma unroll
        for (int half = 0; half < 2; ++half) {
            f32x4 acc[4][2], accm[4][2];
            #pragma unroll
            for (int mt = 0; mt < 4; ++mt)
                #pragma unroll
                for (int nq = 0; nq < 2; ++nq) {
                    acc[mt][nq]  = (f32x4){0.f, 0.f, 0.f, 0.f};
                    accm[mt][nq] = (f32x4){0.f, 0.f, 0.f, 0.f};
                }
            gemmh<16, 1024, 512, HPL>(smem + L_H0, wsb + OFF_W2B3, l4, l16, nt0 + half * 2, acc, accm);
            #pragma unroll
            for (int mt = 0; mt < 4; ++mt)
                #pragma unroll
                for (int nq = 0; nq < 2; ++nq)
                    #pragma unroll
                    for (int q = 0; q < 4; ++q)
                        g2v[mt][half * 2 + nq][q] = acc[mt][nq][q] + accm[mt][nq][q] * SC12;
        }
        __syncthreads();   // all m2 reads done

        #pragma unroll
        for (int mt = 0; mt < 4; ++mt) {
            #pragma unroll
            for (int nq = 0; nq < 4; ++nq) {
                const int col2 = ((nt0 + nq) * 16 + l16) * 2;
                #pragma unroll
                for (int q = 0; q < 4; ++q) {
                    const int row = mt * 16 + l4 * 4 + q;
                    const int off = row * 1024 + (col2 ^ ((row & 7) << 4));
                    if ((mk >> ((mt * 4 + nq) * 4 + q)) & 1ull) {
                        f2h2(g2v[mt][nq][q],
                             (unsigned short*)(smem + L_H0 + off),
                             (unsigned short*)(smem + L_H1 + off));
                    } else {
                        *(unsigned short*)(smem + L_H0 + off) = 0;
                        *(unsigned short*)(smem + L_H1 + off) = 0;
                    }
                }
            }
        }
        __syncthreads();

        // ---- S4: grad = m1 @ W1y^T (2 tiles/wave) ; y -= LR*grad ; refresh y planes
        f32x4 gA = (f32x4){0.f, 0.f, 0.f, 0.f}, gAm = gA;
        f32x4 gB = gA, gBm = gA;
        {
            const char* bh = (const char*)(wsb + OFF_W1Y4);
            const char* bm = (const char*)(wsb + PH + OFF_W1Y4);
            #pragma unroll
            for (int kk = 0; kk < 16; ++kk) {
                const int cb = kk * 64 + l4 * 16;
                const int row = mt4 * 16 + l16;
                const int offA = row * 1024 + (cb ^ ((row & 7) << 4));
                f16x8 ah = *(const f16x8*)(smem + L_H0 + offA);
                f16x8 am = *(const f16x8*)(smem + L_H1 + offA);
                const size_t obA = (size_t)(ntA * 16 + l16) * 1024 + cb;
                const size_t obB = (size_t)(ntB * 16 + l16) * 1024 + cb;
                f16x8 bAh = *(const f16x8*)(bh + obA);
                f16x8 bAm = *(const f16x8*)(bm + obA);
                f16x8 bBh = *(const f16x8*)(bh + obB);
                f16x8 bBm = *(const f16x8*)(bm + obB);
                gA  = __builtin_amdgcn_mfma_f32_16x16x32_f16(ah, bAh, gA,  0, 0, 0);
                gAm = __builtin_amdgcn_mfma_f32_16x16x32_f16(ah, bAm, gAm, 0, 0, 0);
                gAm = __builtin_amdgcn_mfma_f32_16x16x32_f16(am, bAh, gAm, 0, 0, 0);
                gB  = __builtin_amdgcn_mfma_f32_16x16x32_f16(ah, bBh, gB,  0, 0, 0);
                gBm = __builtin_amdgcn_mfma_f32_16x16x32_f16(ah, bBm, gBm, 0, 0, 0);
                gBm = __builtin_amdgcn_mfma_f32_16x16x32_f16(am, bBh, gBm, 0, 0, 0);
            }
        }
        #pragma unroll
        for (int q = 0; q < 4; ++q) {
            ymA[q] = ymA[q] - LRC * (gA[q] + gAm[q] * SC12);
            ymB[q] = ymB[q] - LRC * (gB[q] + gBm[q] * SC12);
        }
        #pragma unroll
        for (int tt2 = 0; tt2 < 2; ++tt2) {
            const int nt = tt2 ? ntB : ntA;
            const f32x4 y = tt2 ? ymB : ymA;
            #pragma unroll
            for (int q = 0; q < 4; ++q) {
                const int row = mt4 * 16 + l4 * 4 + q;
                const int col = nt * 16 + l16;
                const int off = row * 128 + ((col * 2) ^ ((row & 7) << 4));
                f2h2(y[q], (unsigned short*)(smem + L_Y0 + off),
                           (unsigned short*)(smem + L_Y1 + off));
            }
        }
    }

    // write out from fp32 register masters
    #pragma unroll
    for (int tt2 = 0; tt2 < 2; ++tt2) {
        const int nt = tt2 ? ntB : ntA;
        const f32x4 y = tt2 ? ymB : ymA;
        #pragma unroll
        for (int q = 0; q < 4; ++q) {
            const int row = mt4 * 16 + l4 * 4 + q;
            const int col = nt * 16 + l16;
            out[(size_t)(r0 + row) * DYD + col] = y[q];
        }
    }
}

extern "C" void kernel_launch(void* const* d_in, const int* in_sizes, int n_in,
                              void* d_out, int out_size, void* d_ws, size_t ws_size,
                              hipStream_t stream) {
    const float* x  = (const float*)d_in[0];
    const int*   t  = (const int*)d_in[1];
    const float* W1 = (const float*)d_in[2];
    const float* b1 = (const float*)d_in[3];
    const float* W2 = (const float*)d_in[4];
    const float* b2 = (const float*)d_in[5];
    const float* W3 = (const float*)d_in[6];
    // d_in[7] = b3: constant offset, no effect on grad_y
    const int* steps = (const int*)d_in[8];
    float* out = (float*)d_out;
    unsigned short* wsb = (unsigned short*)d_ws;

    const int B = in_sizes[0] / DXD;
    const int nblocks = B / NROWS;

    wconv<<<(PH + 255) / 256, 256, 0, stream>>>(W1, W2, wsb);

    (void)hipFuncSetAttribute((const void*)ebm_mfma,
                              hipFuncAttributeMaxDynamicSharedMemorySize,
                              SMEM_BYTES);
    ebm_mfma<<<nblocks, NTHR, SMEM_BYTES, stream>>>(x, t, W1, b1, W2, b2, W3, steps, wsb, out);
}

// Round 10
// 34299.875 us; speedup vs baseline: 1.5954x; 1.0181x over previous
//
#include <hip/hip_runtime.h>

typedef _Float16 f16x8 __attribute__((ext_vector_type(8)));
typedef float f32x4 __attribute__((ext_vector_type(4)));

#define HID   512
#define DXD   256
#define DYD   64
#define NROWS 64
#define NTHR  512
#define LRC   0.1f
#define TAU1  1e-4f
#define TAU2  1e-4f
#define SC12  2.44140625e-4f   // 2^-12

// ws layout (u16 elements), all fp16 2-plane: h at +0, m(x4096) at +PH
#define OFF_W1YB 0          // [512][64]   W1yB[n][k] = W1[(256+k)*512+n]
#define OFF_W1Y4 32768      // [64][512]   W1y4[d][j] = W1[(256+d)*512+j]
#define OFF_W2B  65536      // [512][512]  W2B[n][k]  = W2[k*512+n]
#define OFF_W2B3 327680     // [512][512]  W2B3[n][k] = W2[n*512+k]
#define PH       589824
#define PHB      1179648    // PH*2 bytes

// LDS layout (bytes)
#define L_H0  0             // act plane h [64][512]*2B row stride 1024; x_f32 [64][256]*4B during stage0
#define L_H1  65536         // act plane m
#define HPL   65536
#define L_Y0  131072        // y plane h [64][64]*2B row stride 128
#define L_Y1  139264        // y plane m
#define YPL   8192
#define L_TL  147456        // 64 ints
#define SMEM_BYTES 147712

// fp16 2-plane split: v = h + m*2^-12 (m scaled x4096 to stay normal).
__device__ __forceinline__ void f2h2(float v, unsigned short* ph, unsigned short* pm) {
    unsigned short hb, mb;
    if (fabsf(v) >= 6.103515625e-05f) {
        _Float16 h = (_Float16)v;
        _Float16 m = (_Float16)((v - (float)h) * 4096.0f);
        hb = __builtin_bit_cast(unsigned short, h);
        mb = __builtin_bit_cast(unsigned short, m);
    } else {
        _Float16 m = (_Float16)(v * 4096.0f);
        hb = 0;
        mb = __builtin_bit_cast(unsigned short, m);
    }
    *ph = hb; *pm = mb;
}

// 4mt x 2nq tile GEMM, fp16 2-plane, 3 exact-product terms, depth-PF B-prefetch.
// acc += Ah*Bh ; accm += Ah*Bm + Am*Bh  (caller folds accm*2^-12)
template<int KSTEPS, int SROWA, int KDIM, int APL_, int PF>
__device__ __forceinline__ void gemmh(const char* ldsA, const unsigned short* B,
                                      int l4, int l16, int ct,
                                      f32x4 acc[4][2], f32x4 accm[4][2])
{
    const char* pb0 = (const char*)B + (size_t)((ct + 0) * 16 + l16) * (KDIM * 2) + l4 * 16;
    const char* pb1 = (const char*)B + (size_t)((ct + 1) * 16 + l16) * (KDIM * 2) + l4 * 16;
    f16x8 bh0[PF], bh1[PF], bm0[PF], bm1[PF];
    #pragma unroll
    for (int p = 0; p < PF; ++p) {
        bh0[p] = *(const f16x8*)(pb0 + p * 64);
        bh1[p] = *(const f16x8*)(pb1 + p * 64);
        bm0[p] = *(const f16x8*)(pb0 + PHB + p * 64);
        bm1[p] = *(const f16x8*)(pb1 + PHB + p * 64);
    }
    #pragma unroll
    for (int kk = 0; kk < KSTEPS; ++kk) {
        const int cb = kk * 64 + l4 * 16;
        const int s = kk % PF;
        f16x8 ah[4], am[4];
        #pragma unroll
        for (int mt = 0; mt < 4; ++mt) {
            const int row = mt * 16 + l16;
            const int off = row * SROWA + (cb ^ ((row & 7) << 4));
            ah[mt] = *(const f16x8*)(ldsA + off);
            am[mt] = *(const f16x8*)(ldsA + APL_ + off);
        }
        f16x8 xh0 = bh0[s], xh1 = bh1[s], xm0 = bm0[s], xm1 = bm1[s];
        if (kk + PF < KSTEPS) {   // refill this slot PF iterations ahead
            bh0[s] = *(const f16x8*)(pb0 + (kk + PF) * 64);
            bh1[s] = *(const f16x8*)(pb1 + (kk + PF) * 64);
            bm0[s] = *(const f16x8*)(pb0 + PHB + (kk + PF) * 64);
            bm1[s] = *(const f16x8*)(pb1 + PHB + (kk + PF) * 64);
        }
        #pragma unroll
        for (int mt = 0; mt < 4; ++mt) {
            acc[mt][0]  = __builtin_amdgcn_mfma_f32_16x16x32_f16(ah[mt], xh0, acc[mt][0],  0, 0, 0);
            accm[mt][0] = __builtin_amdgcn_mfma_f32_16x16x32_f16(ah[mt], xm0, accm[mt][0], 0, 0, 0);
            accm[mt][0] = __builtin_amdgcn_mfma_f32_16x16x32_f16(am[mt], xh0, accm[mt][0], 0, 0, 0);
            acc[mt][1]  = __builtin_amdgcn_mfma_f32_16x16x32_f16(ah[mt], xh1, acc[mt][1],  0, 0, 0);
            accm[mt][1] = __builtin_amdgcn_mfma_f32_16x16x32_f16(ah[mt], xm1, accm[mt][1], 0, 0, 0);
            accm[mt][1] = __builtin_amdgcn_mfma_f32_16x16x32_f16(am[mt], xh1, accm[mt][1], 0, 0, 0);
        }
    }
}

// Serial fp32 recompute of a2[row][col] from fp16-2 LDS h1 + fp16-2 W2B row `col`.
__device__ __attribute__((noinline))
float rescue_s2(const char* smem, int row, int col, float b2n,
                const unsigned short* __restrict__ wsb) {
    float r = b2n;
    const int xr = (row & 7) << 4;
    const int rb = row * 1024;
    const char* wh = (const char*)(wsb + OFF_W2B) + (size_t)col * 1024;
    const char* wm = (const char*)(wsb + PH + OFF_W2B) + (size_t)col * 1024;
    for (int j0 = 0; j0 < HID; j0 += 8) {
        const int off = rb + ((j0 * 2) ^ xr);
        f16x8 h  = *(const f16x8*)(smem + L_H0 + off);
        f16x8 m_ = *(const f16x8*)(smem + L_H1 + off);
        f16x8 bh = *(const f16x8*)(wh + j0 * 2);
        f16x8 bm = *(const f16x8*)(wm + j0 * 2);
        #pragma unroll
        for (int u = 0; u < 8; ++u) {
            float hv = (float)h[u]  + (float)m_[u] * SC12;
            float wv = (float)bh[u] + (float)bm[u] * SC12;
            r = fmaf(hv, wv, r);
        }
    }
    return r;
}

// Serial fp32 recompute of a1[row][col] from exact c and fp16-2 LDS y + W1YB row `col`.
__device__ __attribute__((noinline))
float rescue_s1(const char* smem, int row, int col, float cval,
                const unsigned short* __restrict__ wsb) {
    float r = cval;
    const int xr = (row & 7) << 4;
    const int rb = row * 128;
    const char* wh = (const char*)(wsb + OFF_W1YB) + (size_t)col * 128;
    const char* wm = (const char*)(wsb + PH + OFF_W1YB) + (size_t)col * 128;
    for (int j0 = 0; j0 < DYD; j0 += 8) {
        const int off = rb + ((j0 * 2) ^ xr);
        f16x8 h  = *(const f16x8*)(smem + L_Y0 + off);
        f16x8 m_ = *(const f16x8*)(smem + L_Y1 + off);
        f16x8 bh = *(const f16x8*)(wh + j0 * 2);
        f16x8 bm = *(const f16x8*)(wm + j0 * 2);
        #pragma unroll
        for (int u = 0; u < 8; ++u) {
            float yv = (float)h[u]  + (float)m_[u] * SC12;
            float wv = (float)bh[u] + (float)bm[u] * SC12;
            r = fmaf(yv, wv, r);
        }
    }
    return r;
}

__global__ void wconv(const float* __restrict__ W1, const float* __restrict__ W2,
                      unsigned short* __restrict__ wsb)
{
    int i = blockIdx.x * blockDim.x + threadIdx.x;
    if (i >= PH) return;
    float v;
    if (i < OFF_W1Y4)      { int n = i >> 6, k = i & 63;                    v = W1[(256 + k) * 512 + n]; }
    else if (i < OFF_W2B)  { int j = i - OFF_W1Y4, d = j >> 9, k = j & 511; v = W1[(256 + d) * 512 + k]; }
    else if (i < OFF_W2B3) { int j = i - OFF_W2B,  n = j >> 9, k = j & 511; v = W2[k * 512 + n]; }
    else                   { int j = i - OFF_W2B3, n = j >> 9, k = j & 511; v = W2[n * 512 + k]; }
    f2h2(v, &wsb[i], &wsb[i + PH]);
}

__global__ __launch_bounds__(NTHR, 2)
void ebm_mfma(const float* __restrict__ x, const int* __restrict__ tt,
              const float* __restrict__ W1, const float* __restrict__ b1,
              const float* __restrict__ W2, const float* __restrict__ b2,
              const float* __restrict__ W3, const int* __restrict__ stepsp,
              const unsigned short* __restrict__ wsb, float* __restrict__ out)
{
    extern __shared__ char smem[];

    const int tid  = threadIdx.x;
    const int w    = tid >> 6, lane = tid & 63;
    const int l4   = lane >> 4, l16 = lane & 15;
    const int r0   = blockIdx.x * NROWS;
    const int nt0  = w * 4;          // wave's 4 16-col tiles (64 cols)
    const int nsteps = *stepsp;

    if (tid < NROWS) {
        int tv = tt[r0 + tid];
        ((int*)(smem + L_TL))[tid] = tv < 0 ? 0 : tv;
    }
    // zero y planes (2 * 8KB)
    for (int i = tid; i < 2 * YPL / 4; i += NTHR) ((unsigned*)(smem + L_Y0))[i] = 0u;

    // stage x -> fp32 [64][256] (row stride 1024B) in L_H0/L_H1 region
    {
        const float4* xg = (const float4*)(x + (size_t)r0 * DXD);
        #pragma unroll
        for (int j = 0; j < 8; ++j) {
            int i4 = j * NTHR + tid;          // 4096 float4 = 64 rows * 64
            ((float4*)(smem + L_H0))[i4] = xg[i4];
        }
    }
    __syncthreads();

    // ---- stage 0: c = x @ W1x + b1, EXACT fp32 VALU (r6-identical chain per element)
    f32x4 c_reg[4][4];
    {
        float bb[4];
        #pragma unroll
        for (int nq = 0; nq < 4; ++nq) bb[nq] = b1[(nt0 + nq) * 16 + l16];
        #pragma unroll
        for (int mt = 0; mt < 4; ++mt)
            #pragma unroll
            for (int nq = 0; nq < 4; ++nq)
                c_reg[mt][nq] = (f32x4){bb[nq], bb[nq], bb[nq], bb[nq]};
        for (int i = 0; i < DXD; i += 4) {
            float wv[4][4];
            #pragma unroll
            for (int d = 0; d < 4; ++d)
                #pragma unroll
                for (int nq = 0; nq < 4; ++nq)
                    wv[d][nq] = W1[(size_t)(i + d) * HID + (nt0 + nq) * 16 + l16];
            #pragma unroll
            for (int mt = 0; mt < 4; ++mt)
                #pragma unroll
                for (int q = 0; q < 4; ++q) {
                    const int row = mt * 16 + l4 * 4 + q;
                    float4 xv = *(const float4*)(smem + L_H0 + row * 1024 + i * 4);
                    #pragma unroll
                    for (int nq = 0; nq < 4; ++nq) {
                        c_reg[mt][nq][q] = fmaf(xv.x, wv[0][nq], c_reg[mt][nq][q]);
                        c_reg[mt][nq][q] = fmaf(xv.y, wv[1][nq], c_reg[mt][nq][q]);
                        c_reg[mt][nq][q] = fmaf(xv.z, wv[2][nq], c_reg[mt][nq][q]);
                        c_reg[mt][nq][q] = fmaf(xv.w, wv[3][nq], c_reg[mt][nq][q]);
                    }
                }
        }
    }

    float b2v[4];
    #pragma unroll
    for (int nq = 0; nq < 4; ++nq) b2v[nq] = b2[(nt0 + nq) * 16 + l16];

    // S4 tiles: rows mt4*16.., cols ntA/ntB *16..
    const int mt4 = w >> 1;
    const int ntA = (w & 1) * 2;
    const int ntB = ntA + 1;
    f32x4 ymA = (f32x4){0.f, 0.f, 0.f, 0.f};
    f32x4 ymB = (f32x4){0.f, 0.f, 0.f, 0.f};

    for (int s = 0; s < nsteps; ++s) {
        __syncthreads();   // prev S4 act reads + y writes done

        // ---- S1: a1 = c + y @ W1y ; rescue ties ; h1 = relu -> fp16-2 planes
        unsigned long long mk = 0ull;
        #pragma unroll
        for (int half = 0; half < 2; ++half) {
            f32x4 acc[4][2], accm[4][2];
            #pragma unroll
            for (int mt = 0; mt < 4; ++mt)
                #pragma unroll
                for (int nq = 0; nq < 2; ++nq) {
                    acc[mt][nq]  = c_reg[mt][half * 2 + nq];
                    accm[mt][nq] = (f32x4){0.f, 0.f, 0.f, 0.f};
                }
            gemmh<2, 128, 64, YPL, 2>(smem + L_Y0, wsb + OFF_W1YB, l4, l16, nt0 + half * 2, acc, accm);
            #pragma unroll
            for (int mt = 0; mt < 4; ++mt) {
                #pragma unroll
                for (int nq = 0; nq < 2; ++nq) {
                    const int nqg = half * 2 + nq;
                    const int col = (nt0 + nqg) * 16 + l16;
                    #pragma unroll
                    for (int q = 0; q < 4; ++q) {
                        const int row = mt * 16 + l4 * 4 + q;
                        float v = acc[mt][nq][q] + accm[mt][nq][q] * SC12;
                        if (fabsf(v) < TAU1)
                            v = rescue_s1(smem, row, col, c_reg[mt][nqg][q], wsb);
                        const int off = row * 1024 + ((col * 2) ^ ((row & 7) << 4));
                        if (v > 0.f) {
                            mk |= 1ull << ((mt * 4 + nqg) * 4 + q);
                            f2h2(v, (unsigned short*)(smem + L_H0 + off),
                                    (unsigned short*)(smem + L_H1 + off));
                        } else {
                            *(unsigned short*)(smem + L_H0 + off) = 0;
                            *(unsigned short*)(smem + L_H1 + off) = 0;
                        }
                    }
                }
            }
        }
        __syncthreads();

        // ---- S2: a2 = h1 @ W2 + b2 ; rescue ties -> pos2 bits
        unsigned long long pos2 = 0ull;
        #pragma unroll
        for (int half = 0; half < 2; ++half) {
            f32x4 acc[4][2], accm[4][2];
            #pragma unroll
            for (int mt = 0; mt < 4; ++mt)
                #pragma unroll
                for (int nq = 0; nq < 2; ++nq) {
                    const float bb = b2v[half * 2 + nq];
                    acc[mt][nq]  = (f32x4){bb, bb, bb, bb};
                    accm[mt][nq] = (f32x4){0.f, 0.f, 0.f, 0.f};
                }
            gemmh<16, 1024, 512, HPL, 3>(smem + L_H0, wsb + OFF_W2B, l4, l16, nt0 + half * 2, acc, accm);
            #pragma unroll
            for (int mt = 0; mt < 4; ++mt) {
                #pragma unroll
                for (int nq = 0; nq < 2; ++nq) {
                    const int nqg = half * 2 + nq;
                    const int col = (nt0 + nqg) * 16 + l16;
                    #pragma unroll
                    for (int q = 0; q < 4; ++q) {
                        const int row = mt * 16 + l4 * 4 + q;
                        float v = acc[mt][nq][q] + accm[mt][nq][q] * SC12;
                        if (fabsf(v) < TAU2)
                            v = rescue_s2(smem, row, col, b2v[nqg], wsb);
                        if (v > 0.f) pos2 |= 1ull << ((mt * 4 + nqg) * 4 + q);
                    }
                }
            }
        }
        __syncthreads();   // all h1 reads (gemm + rescue) done

        // S2 epi: m2 = pos ? W3[col][t_row] : 0 -> fp16-2 planes (exact gather)
        #pragma unroll
        for (int mt = 0; mt < 4; ++mt) {
            #pragma unroll
            for (int nq = 0; nq < 4; ++nq) {
                const int col = (nt0 + nq) * 16 + l16;
                #pragma unroll
                for (int q = 0; q < 4; ++q) {
                    const int row = mt * 16 + l4 * 4 + q;
                    const int tv = ((const int*)(smem + L_TL))[row];
                    const int off = row * 1024 + ((col * 2) ^ ((row & 7) << 4));
                    if ((pos2 >> ((mt * 4 + nq) * 4 + q)) & 1ull) {
                        f2h2(W3[col * 4 + tv],
                             (unsigned short*)(smem + L_H0 + off),
                             (unsigned short*)(smem + L_H1 + off));
                    } else {
                        *(unsigned short*)(smem + L_H0 + off) = 0;
                        *(unsigned short*)(smem + L_H1 + off) = 0;
                    }
                }
            }
        }
        __syncthreads();

        // ---- S3: g2 = m2 @ W2^T ; m1 = mask1 ? g2 : 0 -> fp16-2 planes
        f32x4 g2v[4][4];
        #pragma unroll
        for (int half = 0; half < 2; ++half) {
            f32x4 acc[4][2], accm[4][2];
            #pragma unroll
            for (int mt = 0; mt < 4; ++mt)
                #pragma unroll
                for (int nq = 0; nq < 2; ++nq) {
                    acc[mt][nq]  = (f32x4){0.f, 0.f, 0.f, 0.f};
                    accm[mt][nq] = (f32x4){0.f, 0.f, 0.f, 0.f};
                }
            gemmh<16, 1024, 512, HPL, 3>(smem + L_H0, wsb + OFF_W2B3, l4, l16, nt0 + half * 2, acc, accm);
            #pragma unroll
            for (int mt = 0; mt < 4; ++mt)
                #pragma unroll
                for (int nq = 0; nq < 2; ++nq)
                    #pragma unroll
                    for (int q = 0; q < 4; ++q)
                        g2v[mt][half * 2 + nq][q] = acc[mt][nq][q] + accm[mt][nq][q] * SC12;
        }
        __syncthreads();   // all m2 reads done

        #pragma unroll
        for (int mt = 0; mt < 4; ++mt) {
            #pragma unroll
            for (int nq = 0; nq < 4; ++nq) {
                const int col2 = ((nt0 + nq) * 16 + l16) * 2;
                #pragma unroll
                for (int q = 0; q < 4; ++q) {
                    const int row = mt * 16 + l4 * 4 + q;
                    const int off = row * 1024 + (col2 ^ ((row & 7) << 4));
                    if ((mk >> ((mt * 4 + nq) * 4 + q)) & 1ull) {
                        f2h2(g2v[mt][nq][q],
                             (unsigned short*)(smem + L_H0 + off),
                             (unsigned short*)(smem + L_H1 + off));
                    } else {
                        *(unsigned short*)(smem + L_H0 + off) = 0;
                        *(unsigned short*)(smem + L_H1 + off) = 0;
                    }
                }
            }
        }
        __syncthreads();

        // ---- S4: grad = m1 @ W1y^T (2 tiles/wave) ; y -= LR*grad ; refresh y planes
        f32x4 gA = (f32x4){0.f, 0.f, 0.f, 0.f}, gAm = gA;
        f32x4 gB = gA, gBm = gA;
        {
            const char* bh = (const char*)(wsb + OFF_W1Y4);
            const char* bm = (const char*)(wsb + PH + OFF_W1Y4);
            #pragma unroll
            for (int kk = 0; kk < 16; ++kk) {
                const int cb = kk * 64 + l4 * 16;
                const int row = mt4 * 16 + l16;
                const int offA = row * 1024 + (cb ^ ((row & 7) << 4));
                f16x8 ah = *(const f16x8*)(smem + L_H0 + offA);
                f16x8 am = *(const f16x8*)(smem + L_H1 + offA);
                const size_t obA = (size_t)(ntA * 16 + l16) * 1024 + cb;
                const size_t obB = (size_t)(ntB * 16 + l16) * 1024 + cb;
                f16x8 bAh = *(const f16x8*)(bh + obA);
                f16x8 bAm = *(const f16x8*)(bm + obA);
                f16x8 bBh = *(const f16x8*)(bh + obB);
                f16x8 bBm = *(const f16x8*)(bm + obB);
                gA  = __builtin_amdgcn_mfma_f32_16x16x32_f16(ah, bAh, gA,  0, 0, 0);
                gAm = __builtin_amdgcn_mfma_f32_16x16x32_f16(ah, bAm, gAm, 0, 0, 0);
                gAm = __builtin_amdgcn_mfma_f32_16x16x32_f16(am, bAh, gAm, 0, 0, 0);
                gB  = __builtin_amdgcn_mfma_f32_16x16x32_f16(ah, bBh, gB,  0, 0, 0);
                gBm = __builtin_amdgcn_mfma_f32_16x16x32_f16(ah, bBm, gBm, 0, 0, 0);
                gBm = __builtin_amdgcn_mfma_f32_16x16x32_f16(am, bBh, gBm, 0, 0, 0);
            }
        }
        #pragma unroll
        for (int q = 0; q < 4; ++q) {
            ymA[q] = ymA[q] - LRC * (gA[q] + gAm[q] * SC12);
            ymB[q] = ymB[q] - LRC * (gB[q] + gBm[q] * SC12);
        }
        #pragma unroll
        for (int tt2 = 0; tt2 < 2; ++tt2) {
            const int nt = tt2 ? ntB : ntA;
            const f32x4 y = tt2 ? ymB : ymA;
            #pragma unroll
            for (int q = 0; q < 4; ++q) {
                const int row = mt4 * 16 + l4 * 4 + q;
                const int col = nt * 16 + l16;
                const int off = row * 128 + ((col * 2) ^ ((row & 7) << 4));
                f2h2(y[q], (unsigned short*)(smem + L_Y0 + off),
                           (unsigned short*)(smem + L_Y1 + off));
            }
        }
    }

    // write out from fp32 register masters
    #pragma unroll
    for (int tt2 = 0; tt2 < 2; ++tt2) {
        const int nt = tt2 ? ntB : ntA;
        const f32x4 y = tt2 ? ymB : ymA;
        #pragma unroll
        for (int q = 0; q < 4; ++q) {
            const int row = mt4 * 16 + l4 * 4 + q;
            const int col = nt * 16 + l16;
            out[(size_t)(r0 + row) * DYD + col] = y[q];
        }
    }
}

extern "C" void kernel_launch(void* const* d_in, const int* in_sizes, int n_in,
                              void* d_out, int out_size, void* d_ws, size_t ws_size,
                              hipStream_t stream) {
    const float* x  = (const float*)d_in[0];
    const int*   t  = (const int*)d_in[1];
    const float* W1 = (const float*)d_in[2];
    const float* b1 = (const float*)d_in[3];
    const float* W2 = (const float*)d_in[4];
    const float* b2 = (const float*)d_in[5];
    const float* W3 = (const float*)d_in[6];
    // d_in[7] = b3: constant offset, no effect on grad_y
    const int* steps = (const int*)d_in[8];
    float* out = (float*)d_out;
    unsigned short* wsb = (unsigned short*)d_ws;

    const int B = in_sizes[0] / DXD;
    const int nblocks = B / NROWS;

    wconv<<<(PH + 255) / 256, 256, 0, stream>>>(W1, W2, wsb);

    (void)hipFuncSetAttribute((const void*)ebm_mfma,
                              hipFuncAttributeMaxDynamicSharedMemorySize,
                              SMEM_BYTES);
    ebm_mfma<<<nblocks, NTHR, SMEM_BYTES, stream>>>(x, t, W1, b1, W2, b2, W3, steps, wsb, out);
}

// Round 14
// 30550.183 us; speedup vs baseline: 1.7913x; 1.1227x over previous
//
#include <hip/hip_runtime.h>

typedef _Float16 f16x8 __attribute__((ext_vector_type(8)));
typedef float f32x4 __attribute__((ext_vector_type(4)));

#define HID   512
#define DXD   256
#define DYD   64
#define NROWS 64
#define NTHR  1024
#define LRC   0.1f
#define TAU1  1e-4f
#define TAU2  1e-4f
#define SC12  2.44140625e-4f   // 2^-12

// ws layout (u16 elements), all fp16 2-plane: h at +0, m(x4096) at +PH
#define OFF_W1YB 0          // [512][64]   W1yB[n][k] = W1[(256+k)*512+n]
#define OFF_W1Y4 32768      // [64][512]   W1y4[d][j] = W1[(256+d)*512+j]
#define OFF_W2B  65536      // [512][512]  W2B[n][k]  = W2[k*512+n]
#define OFF_W2B3 327680     // [512][512]  W2B3[n][k] = W2[n*512+k]
#define PH       589824

// LDS layout (bytes)
#define L_H0  0             // act plane h [64][512]*2B row stride 1024; x_f32 [64][256]*4B during stage0
#define L_H1  65536         // act plane m
#define HPL   65536
#define L_Y0  131072        // y plane h [64][64]*2B row stride 128
#define L_Y1  139264        // y plane m
#define YPL   8192
#define L_TL  147456        // 64 ints
#define SMEM_BYTES 147712

// fp16 2-plane split: v = h + m*2^-12 (m scaled x4096 to stay normal).
__device__ __forceinline__ void f2h2(float v, unsigned short* ph, unsigned short* pm) {
    unsigned short hb, mb;
    if (fabsf(v) >= 6.103515625e-05f) {
        _Float16 h = (_Float16)v;
        _Float16 m = (_Float16)((v - (float)h) * 4096.0f);
        hb = __builtin_bit_cast(unsigned short, h);
        mb = __builtin_bit_cast(unsigned short, m);
    } else {
        _Float16 m = (_Float16)(v * 4096.0f);
        hb = 0;
        mb = __builtin_bit_cast(unsigned short, m);
    }
    *ph = hb; *pm = mb;
}

// 4mt x 2nq tile GEMM, fp16 2-plane, 3 exact-product terms.
// acc += Ah*Bh ; accm += Ah*Bm + Am*Bh  (caller folds accm*2^-12)
template<int KSTEPS, int SROWA, int KDIM, int APL_>
__device__ __forceinline__ void gemmh(const char* ldsA, const unsigned short* B,
                                      int l4, int l16, int ct,
                                      f32x4 acc[4][2], f32x4 accm[4][2])
{
    const int cb0 = l4 * 16;
    #pragma unroll
    for (int kk = 0; kk < KSTEPS; ++kk) {
        const int cb = kk * 64 + cb0;
        f16x8 ah[4], am[4], bh[2], bm[2];
        #pragma unroll
        for (int mt = 0; mt < 4; ++mt) {
            const int row = mt * 16 + l16;
            const int off = row * SROWA + (cb ^ ((row & 7) << 4));
            ah[mt] = *(const f16x8*)(ldsA + off);
            am[mt] = *(const f16x8*)(ldsA + APL_ + off);
        }
        #pragma unroll
        for (int nq = 0; nq < 2; ++nq) {
            const size_t off = (size_t)((ct + nq) * 16 + l16) * (KDIM * 2) + cb;
            bh[nq] = *(const f16x8*)((const char*)B + off);
            bm[nq] = *(const f16x8*)((const char*)(B + PH) + off);
        }
        #pragma unroll
        for (int mt = 0; mt < 4; ++mt)
            #pragma unroll
            for (int nq = 0; nq < 2; ++nq) {
                acc[mt][nq]  = __builtin_amdgcn_mfma_f32_16x16x32_f16(ah[mt], bh[nq], acc[mt][nq],  0, 0, 0);
                accm[mt][nq] = __builtin_amdgcn_mfma_f32_16x16x32_f16(ah[mt], bm[nq], accm[mt][nq], 0, 0, 0);
                accm[mt][nq] = __builtin_amdgcn_mfma_f32_16x16x32_f16(am[mt], bh[nq], accm[mt][nq], 0, 0, 0);
            }
    }
}

// Serial fp32 recompute of a2[row][col] from fp16-2 LDS h1 + fp16-2 W2B row `col`.
__device__ __attribute__((noinline))
float rescue_s2(const char* smem, int row, int col, float b2n,
                const unsigned short* __restrict__ wsb) {
    float r = b2n;
    const int xr = (row & 7) << 4;
    const int rb = row * 1024;
    const char* wh = (const char*)(wsb + OFF_W2B) + (size_t)col * 1024;
    const char* wm = (const char*)(wsb + PH + OFF_W2B) + (size_t)col * 1024;
    for (int j0 = 0; j0 < HID; j0 += 8) {
        const int off = rb + ((j0 * 2) ^ xr);
        f16x8 h  = *(const f16x8*)(smem + L_H0 + off);
        f16x8 m_ = *(const f16x8*)(smem + L_H1 + off);
        f16x8 bh = *(const f16x8*)(wh + j0 * 2);
        f16x8 bm = *(const f16x8*)(wm + j0 * 2);
        #pragma unroll
        for (int u = 0; u < 8; ++u) {
            float hv = (float)h[u]  + (float)m_[u] * SC12;
            float wv = (float)bh[u] + (float)bm[u] * SC12;
            r = fmaf(hv, wv, r);
        }
    }
    return r;
}

// Serial fp32 recompute of a1[row][col] from exact c and fp16-2 LDS y + W1YB row `col`.
__device__ __attribute__((noinline))
float rescue_s1(const char* smem, int row, int col, float cval,
                const unsigned short* __restrict__ wsb) {
    float r = cval;
    const int xr = (row & 7) << 4;
    const int rb = row * 128;
    const char* wh = (const char*)(wsb + OFF_W1YB) + (size_t)col * 128;
    const char* wm = (const char*)(wsb + PH + OFF_W1YB) + (size_t)col * 128;
    for (int j0 = 0; j0 < DYD; j0 += 8) {
        const int off = rb + ((j0 * 2) ^ xr);
        f16x8 h  = *(const f16x8*)(smem + L_Y0 + off);
        f16x8 m_ = *(const f16x8*)(smem + L_Y1 + off);
        f16x8 bh = *(const f16x8*)(wh + j0 * 2);
        f16x8 bm = *(const f16x8*)(wm + j0 * 2);
        #pragma unroll
        for (int u = 0; u < 8; ++u) {
            float yv = (float)h[u]  + (float)m_[u] * SC12;
            float wv = (float)bh[u] + (float)bm[u] * SC12;
            r = fmaf(yv, wv, r);
        }
    }
    return r;
}

__global__ void wconv(const float* __restrict__ W1, const float* __restrict__ W2,
                      unsigned short* __restrict__ wsb)
{
    int i = blockIdx.x * blockDim.x + threadIdx.x;
    if (i >= PH) return;
    float v;
    if (i < OFF_W1Y4)      { int n = i >> 6, k = i & 63;                    v = W1[(256 + k) * 512 + n]; }
    else if (i < OFF_W2B)  { int j = i - OFF_W1Y4, d = j >> 9, k = j & 511; v = W1[(256 + d) * 512 + k]; }
    else if (i < OFF_W2B3) { int j = i - OFF_W2B,  n = j >> 9, k = j & 511; v = W2[k * 512 + n]; }
    else                   { int j = i - OFF_W2B3, n = j >> 9, k = j & 511; v = W2[n * 512 + k]; }
    f2h2(v, &wsb[i], &wsb[i + PH]);
}

__global__ __launch_bounds__(NTHR, 4)
void ebm_mfma(const float* __restrict__ x, const int* __restrict__ tt,
              const float* __restrict__ W1, const float* __restrict__ b1,
              const float* __restrict__ W2, const float* __restrict__ b2,
              const float* __restrict__ W3, const int* __restrict__ stepsp,
              const unsigned short* __restrict__ wsb, float* __restrict__ out)
{
    extern __shared__ char smem[];

    const int tid  = threadIdx.x;
    const int w    = tid >> 6, lane = tid & 63;   // 16 waves
    const int l4   = lane >> 4, l16 = lane & 15;
    const int r0   = blockIdx.x * NROWS;
    const int nt0  = w * 2;          // wave's 2 16-col tiles (32 cols)
    const int nsteps = *stepsp;

    if (tid < NROWS) {
        int tv = tt[r0 + tid];
        ((int*)(smem + L_TL))[tid] = tv < 0 ? 0 : tv;
    }
    // zero y planes (2 * 8KB)
    for (int i = tid; i < 2 * YPL / 4; i += NTHR) ((unsigned*)(smem + L_Y0))[i] = 0u;

    // stage x -> fp32 [64][256] (row stride 1024B) in L_H0/L_H1 region
    {
        const float4* xg = (const float4*)(x + (size_t)r0 * DXD);
        #pragma unroll
        for (int j = 0; j < 4; ++j) {
            int i4 = j * NTHR + tid;          // 4096 float4 = 64 rows * 64
            ((float4*)(smem + L_H0))[i4] = xg[i4];
        }
    }
    __syncthreads();

    // ---- stage 0: c = x @ W1x + b1, EXACT fp32 VALU (per-element chain identical to r6/r9)
    f32x4 c_reg[4][2];
    {
        float bb[2];
        #pragma unroll
        for (int nq = 0; nq < 2; ++nq) bb[nq] = b1[(nt0 + nq) * 16 + l16];
        #pragma unroll
        for (int mt = 0; mt < 4; ++mt)
            #pragma unroll
            for (int nq = 0; nq < 2; ++nq)
                c_reg[mt][nq] = (f32x4){bb[nq], bb[nq], bb[nq], bb[nq]};
        for (int i = 0; i < DXD; i += 4) {
            float wv[4][2];
            #pragma unroll
            for (int d = 0; d < 4; ++d)
                #pragma unroll
                for (int nq = 0; nq < 2; ++nq)
                    wv[d][nq] = W1[(size_t)(i + d) * HID + (nt0 + nq) * 16 + l16];
            #pragma unroll
            for (int mt = 0; mt < 4; ++mt)
                #pragma unroll
                for (int q = 0; q < 4; ++q) {
                    const int row = mt * 16 + l4 * 4 + q;
                    float4 xv = *(const float4*)(smem + L_H0 + row * 1024 + i * 4);
                    #pragma unroll
                    for (int nq = 0; nq < 2; ++nq) {
                        c_reg[mt][nq][q] = fmaf(xv.x, wv[0][nq], c_reg[mt][nq][q]);
                        c_reg[mt][nq][q] = fmaf(xv.y, wv[1][nq], c_reg[mt][nq][q]);
                        c_reg[mt][nq][q] = fmaf(xv.z, wv[2][nq], c_reg[mt][nq][q]);
                        c_reg[mt][nq][q] = fmaf(xv.w, wv[3][nq], c_reg[mt][nq][q]);
                    }
                }
        }
    }

    float b2v[2];
    #pragma unroll
    for (int nq = 0; nq < 2; ++nq) b2v[nq] = b2[(nt0 + nq) * 16 + l16];

    // S4: one 16x16 tile per wave: rows mt4*16.., cols nt4*16..
    const int mt4 = w >> 2;
    const int nt4 = w & 3;
    f32x4 ym = (f32x4){0.f, 0.f, 0.f, 0.f};

    for (int s = 0; s < nsteps; ++s) {
        __syncthreads();   // prev S4 act reads + y writes done

        // ---- S1: a1 = c + y @ W1y ; rescue ties ; h1 = relu -> fp16-2 planes
        unsigned mk = 0u;
        {
            f32x4 acc[4][2], accm[4][2];
            #pragma unroll
            for (int mt = 0; mt < 4; ++mt)
                #pragma unroll
                for (int nq = 0; nq < 2; ++nq) {
                    acc[mt][nq]  = c_reg[mt][nq];
                    accm[mt][nq] = (f32x4){0.f, 0.f, 0.f, 0.f};
                }
            gemmh<2, 128, 64, YPL>(smem + L_Y0, wsb + OFF_W1YB, l4, l16, nt0, acc, accm);
            #pragma unroll
            for (int mt = 0; mt < 4; ++mt) {
                #pragma unroll
                for (int nq = 0; nq < 2; ++nq) {
                    const int col = (nt0 + nq) * 16 + l16;
                    #pragma unroll
                    for (int q = 0; q < 4; ++q) {
                        const int row = mt * 16 + l4 * 4 + q;
                        float v = acc[mt][nq][q] + accm[mt][nq][q] * SC12;
                        if (fabsf(v) < TAU1)
                            v = rescue_s1(smem, row, col, c_reg[mt][nq][q], wsb);
                        const int off = row * 1024 + ((col * 2) ^ ((row & 7) << 4));
                        if (v > 0.f) {
                            mk |= 1u << ((mt * 2 + nq) * 4 + q);
                            f2h2(v, (unsigned short*)(smem + L_H0 + off),
                                    (unsigned short*)(smem + L_H1 + off));
                        } else {
                            *(unsigned short*)(smem + L_H0 + off) = 0;
                            *(unsigned short*)(smem + L_H1 + off) = 0;
                        }
                    }
                }
            }
        }
        __syncthreads();

        // ---- S2: a2 = h1 @ W2 + b2 ; rescue ties -> pos2 bits
        unsigned pos2 = 0u;
        {
            f32x4 acc[4][2], accm[4][2];
            #pragma unroll
            for (int mt = 0; mt < 4; ++mt)
                #pragma unroll
                for (int nq = 0; nq < 2; ++nq) {
                    acc[mt][nq]  = (f32x4){b2v[nq], b2v[nq], b2v[nq], b2v[nq]};
                    accm[mt][nq] = (f32x4){0.f, 0.f, 0.f, 0.f};
                }
            gemmh<16, 1024, 512, HPL>(smem + L_H0, wsb + OFF_W2B, l4, l16, nt0, acc, accm);
            #pragma unroll
            for (int mt = 0; mt < 4; ++mt) {
                #pragma unroll
                for (int nq = 0; nq < 2; ++nq) {
                    const int col = (nt0 + nq) * 16 + l16;
                    #pragma unroll
                    for (int q = 0; q < 4; ++q) {
                        const int row = mt * 16 + l4 * 4 + q;
                        float v = acc[mt][nq][q] + accm[mt][nq][q] * SC12;
                        if (fabsf(v) < TAU2)
                            v = rescue_s2(smem, row, col, b2v[nq], wsb);
                        if (v > 0.f) pos2 |= 1u << ((mt * 2 + nq) * 4 + q);
                    }
                }
            }
        }
        __syncthreads();   // all h1 reads (gemm + rescue) done

        // S2 epi: m2 = pos ? W3[col][t_row] : 0 -> fp16-2 planes (exact gather)
        #pragma unroll
        for (int mt = 0; mt < 4; ++mt) {
            #pragma unroll
            for (int nq = 0; nq < 2; ++nq) {
                const int col = (nt0 + nq) * 16 + l16;
                #pragma unroll
                for (int q = 0; q < 4; ++q) {
                    const int row = mt * 16 + l4 * 4 + q;
                    const int tv = ((const int*)(smem + L_TL))[row];
                    const int off = row * 1024 + ((col * 2) ^ ((row & 7) << 4));
                    if ((pos2 >> ((mt * 2 + nq) * 4 + q)) & 1u) {
                        f2h2(W3[col * 4 + tv],
                             (unsigned short*)(smem + L_H0 + off),
                             (unsigned short*)(smem + L_H1 + off));
                    } else {
                        *(unsigned short*)(smem + L_H0 + off) = 0;
                        *(unsigned short*)(smem + L_H1 + off) = 0;
                    }
                }
            }
        }
        __syncthreads();

        // ---- S3: g2 = m2 @ W2^T ; m1 = mask1 ? g2 : 0 -> fp16-2 planes
        f32x4 g2v[4][2];
        {
            f32x4 acc[4][2], accm[4][2];
            #pragma unroll
            for (int mt = 0; mt < 4; ++mt)
                #pragma unroll
                for (int nq = 0; nq < 2; ++nq) {
                    acc[mt][nq]  = (f32x4){0.f, 0.f, 0.f, 0.f};
                    accm[mt][nq] = (f32x4){0.f, 0.f, 0.f, 0.f};
                }
            gemmh<16, 1024, 512, HPL>(smem + L_H0, wsb + OFF_W2B3, l4, l16, nt0, acc, accm);
            #pragma unroll
            for (int mt = 0; mt < 4; ++mt)
                #pragma unroll
                for (int nq = 0; nq < 2; ++nq)
                    #pragma unroll
                    for (int q = 0; q < 4; ++q)
                        g2v[mt][nq][q] = acc[mt][nq][q] + accm[mt][nq][q] * SC12;
        }
        __syncthreads();   // all m2 reads done

        #pragma unroll
        for (int mt = 0; mt < 4; ++mt) {
            #pragma unroll
            for (int nq = 0; nq < 2; ++nq) {
                const int col2 = ((nt0 + nq) * 16 + l16) * 2;
                #pragma unroll
                for (int q = 0; q < 4; ++q) {
                    const int row = mt * 16 + l4 * 4 + q;
                    const int off = row * 1024 + (col2 ^ ((row & 7) << 4));
                    if ((mk >> ((mt * 2 + nq) * 4 + q)) & 1u) {
                        f2h2(g2v[mt][nq][q],
                             (unsigned short*)(smem + L_H0 + off),
                             (unsigned short*)(smem + L_H1 + off));
                    } else {
                        *(unsigned short*)(smem + L_H0 + off) = 0;
                        *(unsigned short*)(smem + L_H1 + off) = 0;
                    }
                }
            }
        }
        __syncthreads();

        // ---- S4: grad = m1 @ W1y^T (1 tile/wave) ; y -= LR*grad ; refresh y planes
        f32x4 gA = (f32x4){0.f, 0.f, 0.f, 0.f}, gAm = gA;
        {
            const char* bh = (const char*)(wsb + OFF_W1Y4);
            const char* bm = (const char*)(wsb + PH + OFF_W1Y4);
            #pragma unroll
            for (int kk = 0; kk < 16; ++kk) {
                const int cb = kk * 64 + l4 * 16;
                const int row = mt4 * 16 + l16;
                const int offA = row * 1024 + (cb ^ ((row & 7) << 4));
                f16x8 ah = *(const f16x8*)(smem + L_H0 + offA);
                f16x8 am = *(const f16x8*)(smem + L_H1 + offA);
                const size_t obA = (size_t)(nt4 * 16 + l16) * 1024 + cb;
                f16x8 bAh = *(const f16x8*)(bh + obA);
                f16x8 bAm = *(const f16x8*)(bm + obA);
                gA  = __builtin_amdgcn_mfma_f32_16x16x32_f16(ah, bAh, gA,  0, 0, 0);
                gAm = __builtin_amdgcn_mfma_f32_16x16x32_f16(ah, bAm, gAm, 0, 0, 0);
                gAm = __builtin_amdgcn_mfma_f32_16x16x32_f16(am, bAh, gAm, 0, 0, 0);
            }
        }
        #pragma unroll
        for (int q = 0; q < 4; ++q)
            ym[q] = ym[q] - LRC * (gA[q] + gAm[q] * SC12);
        #pragma unroll
        for (int q = 0; q < 4; ++q) {
            const int row = mt4 * 16 + l4 * 4 + q;
            const int col = nt4 * 16 + l16;
            const int off = row * 128 + ((col * 2) ^ ((row & 7) << 4));
            f2h2(ym[q], (unsigned short*)(smem + L_Y0 + off),
                        (unsigned short*)(smem + L_Y1 + off));
        }
    }

    // write out from fp32 register master
    #pragma unroll
    for (int q = 0; q < 4; ++q) {
        const int row = mt4 * 16 + l4 * 4 + q;
        const int col = nt4 * 16 + l16;
        out[(size_t)(r0 + row) * DYD + col] = ym[q];
    }
}

extern "C" void kernel_launch(void* const* d_in, const int* in_sizes, int n_in,
                              void* d_out, int out_size, void* d_ws, size_t ws_size,
                              hipStream_t stream) {
    const float* x  = (const float*)d_in[0];
    const int*   t  = (const int*)d_in[1];
    const float* W1 = (const float*)d_in[2];
    const float* b1 = (const float*)d_in[3];
    const float* W2 = (const float*)d_in[4];
    const float* b2 = (const float*)d_in[5];
    const float* W3 = (const float*)d_in[6];
    // d_in[7] = b3: constant offset, no effect on grad_y
    const int* steps = (const int*)d_in[8];
    float* out = (float*)d_out;
    unsigned short* wsb = (unsigned short*)d_ws;

    const int B = in_sizes[0] / DXD;
    const int nblocks = B / NROWS;

    wconv<<<(PH + 255) / 256, 256, 0, stream>>>(W1, W2, wsb);

    (void)hipFuncSetAttribute((const void*)ebm_mfma,
                              hipFuncAttributeMaxDynamicSharedMemorySize,
                              SMEM_BYTES);
    ebm_mfma<<<nblocks, NTHR, SMEM_BYTES, stream>>>(x, t, W1, b1, W2, b2, W3, steps, wsb, out);
}

// Round 15
// 30097.247 us; speedup vs baseline: 1.8182x; 1.0150x over previous
//
#include <hip/hip_runtime.h>

typedef _Float16 f16x8 __attribute__((ext_vector_type(8)));
typedef float f32x4 __attribute__((ext_vector_type(4)));

#define HID   512
#define DXD   256
#define DYD   64
#define NROWS 64
#define NTHR  1024
#define LRC   0.1f
#define TAU1  1e-4f
#define TAU2  1e-4f
#define SC12  2.44140625e-4f   // 2^-12

// ws layout (u16 elements), all fp16 2-plane: h at +0, m(x4096) at +PH
#define OFF_W1YB 0          // [512][64]   W1yB[n][k] = W1[(256+k)*512+n]
#define OFF_W1Y4 32768      // [64][512]   W1y4[d][j] = W1[(256+d)*512+j]
#define OFF_W2B  65536      // [512][512]  W2B[n][k]  = W2[k*512+n]
#define OFF_W2B3 327680     // [512][512]  W2B3[n][k] = W2[n*512+k]
#define PH       589824

// LDS layout (bytes) — STATIC shared so the register allocator sees 1 block/CU
#define L_H0  0             // act plane h [64][512]*2B row stride 1024; x_f32 [64][256]*4B during stage0
#define L_H1  65536         // act plane m
#define HPL   65536
#define L_Y0  131072        // y plane h [64][64]*2B row stride 128
#define L_Y1  139264        // y plane m
#define YPL   8192
#define L_TL  147456        // 64 ints
#define SMEM_BYTES 147712

// fp16 2-plane split: v = h + m*2^-12 (m scaled x4096 to stay normal).
__device__ __forceinline__ void f2h2(float v, unsigned short* ph, unsigned short* pm) {
    unsigned short hb, mb;
    if (fabsf(v) >= 6.103515625e-05f) {
        _Float16 h = (_Float16)v;
        _Float16 m = (_Float16)((v - (float)h) * 4096.0f);
        hb = __builtin_bit_cast(unsigned short, h);
        mb = __builtin_bit_cast(unsigned short, m);
    } else {
        _Float16 m = (_Float16)(v * 4096.0f);
        hb = 0;
        mb = __builtin_bit_cast(unsigned short, m);
    }
    *ph = hb; *pm = mb;
}

// 4mt x 1nq tile GEMM, fp16 2-plane, 3 exact-product terms (low-pressure pass).
// acc += Ah*Bh ; accm += Ah*Bm + Am*Bh  (caller folds accm*2^-12)
// Per-element MFMA chain identical to the fused 2-nq version (r14).
template<int KSTEPS, int SROWA, int KDIM, int APL_>
__device__ __forceinline__ void gemmh1(const char* ldsA, const unsigned short* B,
                                       int l4, int l16, int ct,
                                       f32x4 acc[4], f32x4 accm[4])
{
    const int cb0 = l4 * 16;
    #pragma unroll
    for (int kk = 0; kk < KSTEPS; ++kk) {
        const int cb = kk * 64 + cb0;
        f16x8 ah[4], am[4];
        #pragma unroll
        for (int mt = 0; mt < 4; ++mt) {
            const int row = mt * 16 + l16;
            const int off = row * SROWA + (cb ^ ((row & 7) << 4));
            ah[mt] = *(const f16x8*)(ldsA + off);
            am[mt] = *(const f16x8*)(ldsA + APL_ + off);
        }
        const size_t off = (size_t)(ct * 16 + l16) * (KDIM * 2) + cb;
        f16x8 bh = *(const f16x8*)((const char*)B + off);
        f16x8 bm = *(const f16x8*)((const char*)(B + PH) + off);
        #pragma unroll
        for (int mt = 0; mt < 4; ++mt) {
            acc[mt]  = __builtin_amdgcn_mfma_f32_16x16x32_f16(ah[mt], bh, acc[mt],  0, 0, 0);
            accm[mt] = __builtin_amdgcn_mfma_f32_16x16x32_f16(ah[mt], bm, accm[mt], 0, 0, 0);
            accm[mt] = __builtin_amdgcn_mfma_f32_16x16x32_f16(am[mt], bh, accm[mt], 0, 0, 0);
        }
    }
}

// Serial fp32 recompute of a2[row][col] from fp16-2 LDS h1 + fp16-2 W2B row `col`.
__device__ __attribute__((noinline))
float rescue_s2(const char* smem, int row, int col, float b2n,
                const unsigned short* __restrict__ wsb) {
    float r = b2n;
    const int xr = (row & 7) << 4;
    const int rb = row * 1024;
    const char* wh = (const char*)(wsb + OFF_W2B) + (size_t)col * 1024;
    const char* wm = (const char*)(wsb + PH + OFF_W2B) + (size_t)col * 1024;
    for (int j0 = 0; j0 < HID; j0 += 8) {
        const int off = rb + ((j0 * 2) ^ xr);
        f16x8 h  = *(const f16x8*)(smem + L_H0 + off);
        f16x8 m_ = *(const f16x8*)(smem + L_H1 + off);
        f16x8 bh = *(const f16x8*)(wh + j0 * 2);
        f16x8 bm = *(const f16x8*)(wm + j0 * 2);
        #pragma unroll
        for (int u = 0; u < 8; ++u) {
            float hv = (float)h[u]  + (float)m_[u] * SC12;
            float wv = (float)bh[u] + (float)bm[u] * SC12;
            r = fmaf(hv, wv, r);
        }
    }
    return r;
}

// Serial fp32 recompute of a1[row][col] from exact c and fp16-2 LDS y + W1YB row `col`.
__device__ __attribute__((noinline))
float rescue_s1(const char* smem, int row, int col, float cval,
                const unsigned short* __restrict__ wsb) {
    float r = cval;
    const int xr = (row & 7) << 4;
    const int rb = row * 128;
    const char* wh = (const char*)(wsb + OFF_W1YB) + (size_t)col * 128;
    const char* wm = (const char*)(wsb + PH + OFF_W1YB) + (size_t)col * 128;
    for (int j0 = 0; j0 < DYD; j0 += 8) {
        const int off = rb + ((j0 * 2) ^ xr);
        f16x8 h  = *(const f16x8*)(smem + L_Y0 + off);
        f16x8 m_ = *(const f16x8*)(smem + L_Y1 + off);
        f16x8 bh = *(const f16x8*)(wh + j0 * 2);
        f16x8 bm = *(const f16x8*)(wm + j0 * 2);
        #pragma unroll
        for (int u = 0; u < 8; ++u) {
            float yv = (float)h[u]  + (float)m_[u] * SC12;
            float wv = (float)bh[u] + (float)bm[u] * SC12;
            r = fmaf(yv, wv, r);
        }
    }
    return r;
}

__global__ void wconv(const float* __restrict__ W1, const float* __restrict__ W2,
                      unsigned short* __restrict__ wsb)
{
    int i = blockIdx.x * blockDim.x + threadIdx.x;
    if (i >= PH) return;
    float v;
    if (i < OFF_W1Y4)      { int n = i >> 6, k = i & 63;                    v = W1[(256 + k) * 512 + n]; }
    else if (i < OFF_W2B)  { int j = i - OFF_W1Y4, d = j >> 9, k = j & 511; v = W1[(256 + d) * 512 + k]; }
    else if (i < OFF_W2B3) { int j = i - OFF_W2B,  n = j >> 9, k = j & 511; v = W2[k * 512 + n]; }
    else                   { int j = i - OFF_W2B3, n = j >> 9, k = j & 511; v = W2[n * 512 + k]; }
    f2h2(v, &wsb[i], &wsb[i + PH]);
}

__global__ __launch_bounds__(NTHR, 4)
void ebm_mfma(const float* __restrict__ x, const int* __restrict__ tt,
              const float* __restrict__ W1, const float* __restrict__ b1,
              const float* __restrict__ W2, const float* __restrict__ b2,
              const float* __restrict__ W3, const int* __restrict__ stepsp,
              const unsigned short* __restrict__ wsb, float* __restrict__ out)
{
    __shared__ __align__(16) char smem[SMEM_BYTES];   // STATIC: allocator sees 1 block/CU

    const int tid  = threadIdx.x;
    const int w    = tid >> 6, lane = tid & 63;   // 16 waves
    const int l4   = lane >> 4, l16 = lane & 15;
    const int r0   = blockIdx.x * NROWS;
    const int nt0  = w * 2;          // wave's 2 16-col tiles (32 cols)
    const int nsteps = *stepsp;

    if (tid < NROWS) {
        int tv = tt[r0 + tid];
        ((int*)(smem + L_TL))[tid] = tv < 0 ? 0 : tv;
    }
    // zero y planes (2 * 8KB)
    for (int i = tid; i < 2 * YPL / 4; i += NTHR) ((unsigned*)(smem + L_Y0))[i] = 0u;

    // stage x -> fp32 [64][256] (row stride 1024B) in L_H0/L_H1 region
    {
        const float4* xg = (const float4*)(x + (size_t)r0 * DXD);
        #pragma unroll
        for (int j = 0; j < 4; ++j) {
            int i4 = j * NTHR + tid;          // 4096 float4 = 64 rows * 64
            ((float4*)(smem + L_H0))[i4] = xg[i4];
        }
    }
    __syncthreads();

    // ---- stage 0: c = x @ W1x + b1, EXACT fp32 VALU (per-element chain identical to r6/r9)
    f32x4 c_reg[4][2];
    {
        float bb[2];
        #pragma unroll
        for (int nq = 0; nq < 2; ++nq) bb[nq] = b1[(nt0 + nq) * 16 + l16];
        #pragma unroll
        for (int mt = 0; mt < 4; ++mt)
            #pragma unroll
            for (int nq = 0; nq < 2; ++nq)
                c_reg[mt][nq] = (f32x4){bb[nq], bb[nq], bb[nq], bb[nq]};
        for (int i = 0; i < DXD; i += 4) {
            float wv[4][2];
            #pragma unroll
            for (int d = 0; d < 4; ++d)
                #pragma unroll
                for (int nq = 0; nq < 2; ++nq)
                    wv[d][nq] = W1[(size_t)(i + d) * HID + (nt0 + nq) * 16 + l16];
            #pragma unroll
            for (int mt = 0; mt < 4; ++mt)
                #pragma unroll
                for (int q = 0; q < 4; ++q) {
                    const int row = mt * 16 + l4 * 4 + q;
                    float4 xv = *(const float4*)(smem + L_H0 + row * 1024 + i * 4);
                    #pragma unroll
                    for (int nq = 0; nq < 2; ++nq) {
                        c_reg[mt][nq][q] = fmaf(xv.x, wv[0][nq], c_reg[mt][nq][q]);
                        c_reg[mt][nq][q] = fmaf(xv.y, wv[1][nq], c_reg[mt][nq][q]);
                        c_reg[mt][nq][q] = fmaf(xv.z, wv[2][nq], c_reg[mt][nq][q]);
                        c_reg[mt][nq][q] = fmaf(xv.w, wv[3][nq], c_reg[mt][nq][q]);
                    }
                }
        }
    }

    float b2v[2];
    #pragma unroll
    for (int nq = 0; nq < 2; ++nq) b2v[nq] = b2[(nt0 + nq) * 16 + l16];

    // S4: one 16x16 tile per wave: rows mt4*16.., cols nt4*16..
    const int mt4 = w >> 2;
    const int nt4 = w & 3;
    f32x4 ym = (f32x4){0.f, 0.f, 0.f, 0.f};

    for (int s = 0; s < nsteps; ++s) {
        __syncthreads();   // prev S4 act reads + y writes done

        // ---- S1: a1 = c + y @ W1y ; rescue ties ; h1 = relu -> fp16-2 planes
        // Two low-pressure passes (nq=0 then nq=1); per-element chains unchanged.
        unsigned mk = 0u;
        {   // pass nq=0
            f32x4 acc[4], accm[4];
            #pragma unroll
            for (int mt = 0; mt < 4; ++mt) { acc[mt] = c_reg[mt][0]; accm[mt] = (f32x4){0.f,0.f,0.f,0.f}; }
            gemmh1<2, 128, 64, YPL>(smem + L_Y0, wsb + OFF_W1YB, l4, l16, nt0 + 0, acc, accm);
            const int col = (nt0 + 0) * 16 + l16;
            #pragma unroll
            for (int mt = 0; mt < 4; ++mt) {
                #pragma unroll
                for (int q = 0; q < 4; ++q) {
                    const int row = mt * 16 + l4 * 4 + q;
                    float v = acc[mt][q] + accm[mt][q] * SC12;
                    if (fabsf(v) < TAU1) v = rescue_s1(smem, row, col, c_reg[mt][0][q], wsb);
                    const int off = row * 1024 + ((col * 2) ^ ((row & 7) << 4));
                    if (v > 0.f) {
                        mk |= 1u << ((mt * 2 + 0) * 4 + q);
                        f2h2(v, (unsigned short*)(smem + L_H0 + off), (unsigned short*)(smem + L_H1 + off));
                    } else {
                        *(unsigned short*)(smem + L_H0 + off) = 0;
                        *(unsigned short*)(smem + L_H1 + off) = 0;
                    }
                }
            }
        }
        __builtin_amdgcn_sched_barrier(0);
        {   // pass nq=1
            f32x4 acc[4], accm[4];
            #pragma unroll
            for (int mt = 0; mt < 4; ++mt) { acc[mt] = c_reg[mt][1]; accm[mt] = (f32x4){0.f,0.f,0.f,0.f}; }
            gemmh1<2, 128, 64, YPL>(smem + L_Y0, wsb + OFF_W1YB, l4, l16, nt0 + 1, acc, accm);
            const int col = (nt0 + 1) * 16 + l16;
            #pragma unroll
            for (int mt = 0; mt < 4; ++mt) {
                #pragma unroll
                for (int q = 0; q < 4; ++q) {
                    const int row = mt * 16 + l4 * 4 + q;
                    float v = acc[mt][q] + accm[mt][q] * SC12;
                    if (fabsf(v) < TAU1) v = rescue_s1(smem, row, col, c_reg[mt][1][q], wsb);
                    const int off = row * 1024 + ((col * 2) ^ ((row & 7) << 4));
                    if (v > 0.f) {
                        mk |= 1u << ((mt * 2 + 1) * 4 + q);
                        f2h2(v, (unsigned short*)(smem + L_H0 + off), (unsigned short*)(smem + L_H1 + off));
                    } else {
                        *(unsigned short*)(smem + L_H0 + off) = 0;
                        *(unsigned short*)(smem + L_H1 + off) = 0;
                    }
                }
            }
        }
        __syncthreads();

        // ---- S2: a2 = h1 @ W2 + b2 ; rescue ties -> pos2 bits (two passes)
        unsigned pos2 = 0u;
        {   // pass nq=0
            f32x4 acc[4], accm[4];
            #pragma unroll
            for (int mt = 0; mt < 4; ++mt) { acc[mt] = (f32x4){b2v[0],b2v[0],b2v[0],b2v[0]}; accm[mt] = (f32x4){0.f,0.f,0.f,0.f}; }
            gemmh1<16, 1024, 512, HPL>(smem + L_H0, wsb + OFF_W2B, l4, l16, nt0 + 0, acc, accm);
            const int col = (nt0 + 0) * 16 + l16;
            #pragma unroll
            for (int mt = 0; mt < 4; ++mt) {
                #pragma unroll
                for (int q = 0; q < 4; ++q) {
                    const int row = mt * 16 + l4 * 4 + q;
                    float v = acc[mt][q] + accm[mt][q] * SC12;
                    if (fabsf(v) < TAU2) v = rescue_s2(smem, row, col, b2v[0], wsb);
                    if (v > 0.f) pos2 |= 1u << ((mt * 2 + 0) * 4 + q);
                }
            }
        }
        __builtin_amdgcn_sched_barrier(0);
        {   // pass nq=1
            f32x4 acc[4], accm[4];
            #pragma unroll
            for (int mt = 0; mt < 4; ++mt) { acc[mt] = (f32x4){b2v[1],b2v[1],b2v[1],b2v[1]}; accm[mt] = (f32x4){0.f,0.f,0.f,0.f}; }
            gemmh1<16, 1024, 512, HPL>(smem + L_H0, wsb + OFF_W2B, l4, l16, nt0 + 1, acc, accm);
            const int col = (nt0 + 1) * 16 + l16;
            #pragma unroll
            for (int mt = 0; mt < 4; ++mt) {
                #pragma unroll
                for (int q = 0; q < 4; ++q) {
                    const int row = mt * 16 + l4 * 4 + q;
                    float v = acc[mt][q] + accm[mt][q] * SC12;
                    if (fabsf(v) < TAU2) v = rescue_s2(smem, row, col, b2v[1], wsb);
                    if (v > 0.f) pos2 |= 1u << ((mt * 2 + 1) * 4 + q);
                }
            }
        }
        __syncthreads();   // all h1 reads (gemm + rescue) done

        // S2 epi: m2 = pos ? W3[col][t_row] : 0 -> fp16-2 planes (exact gather)
        #pragma unroll
        for (int mt = 0; mt < 4; ++mt) {
            #pragma unroll
            for (int nq = 0; nq < 2; ++nq) {
                const int col = (nt0 + nq) * 16 + l16;
                #pragma unroll
                for (int q = 0; q < 4; ++q) {
                    const int row = mt * 16 + l4 * 4 + q;
                    const int tv = ((const int*)(smem + L_TL))[row];
                    const int off = row * 1024 + ((col * 2) ^ ((row & 7) << 4));
                    if ((pos2 >> ((mt * 2 + nq) * 4 + q)) & 1u) {
                        f2h2(W3[col * 4 + tv],
                             (unsigned short*)(smem + L_H0 + off),
                             (unsigned short*)(smem + L_H1 + off));
                    } else {
                        *(unsigned short*)(smem + L_H0 + off) = 0;
                        *(unsigned short*)(smem + L_H1 + off) = 0;
                    }
                }
            }
        }
        __syncthreads();

        // ---- S3: g2 = m2 @ W2^T (two passes; g2 held in 2x16 regs) ; m1 -> planes
        f32x4 g2vA[4], g2vB[4];
        {   // pass nq=0
            f32x4 acc[4], accm[4];
            #pragma unroll
            for (int mt = 0; mt < 4; ++mt) { acc[mt] = (f32x4){0.f,0.f,0.f,0.f}; accm[mt] = (f32x4){0.f,0.f,0.f,0.f}; }
            gemmh1<16, 1024, 512, HPL>(smem + L_H0, wsb + OFF_W2B3, l4, l16, nt0 + 0, acc, accm);
            #pragma unroll
            for (int mt = 0; mt < 4; ++mt)
                #pragma unroll
                for (int q = 0; q < 4; ++q)
                    g2vA[mt][q] = acc[mt][q] + accm[mt][q] * SC12;
        }
        __builtin_amdgcn_sched_barrier(0);
        {   // pass nq=1
            f32x4 acc[4], accm[4];
            #pragma unroll
            for (int mt = 0; mt < 4; ++mt) { acc[mt] = (f32x4){0.f,0.f,0.f,0.f}; accm[mt] = (f32x4){0.f,0.f,0.f,0.f}; }
            gemmh1<16, 1024, 512, HPL>(smem + L_H0, wsb + OFF_W2B3, l4, l16, nt0 + 1, acc, accm);
            #pragma unroll
            for (int mt = 0; mt < 4; ++mt)
                #pragma unroll
                for (int q = 0; q < 4; ++q)
                    g2vB[mt][q] = acc[mt][q] + accm[mt][q] * SC12;
        }
        __syncthreads();   // all m2 reads done

        #pragma unroll
        for (int mt = 0; mt < 4; ++mt) {
            {   // nq=0 from g2vA
                const int col2 = ((nt0 + 0) * 16 + l16) * 2;
                #pragma unroll
                for (int q = 0; q < 4; ++q) {
                    const int row = mt * 16 + l4 * 4 + q;
                    const int off = row * 1024 + (col2 ^ ((row & 7) << 4));
                    if ((mk >> ((mt * 2 + 0) * 4 + q)) & 1u) {
                        f2h2(g2vA[mt][q],
                             (unsigned short*)(smem + L_H0 + off),
                             (unsigned short*)(smem + L_H1 + off));
                    } else {
                        *(unsigned short*)(smem + L_H0 + off) = 0;
                        *(unsigned short*)(smem + L_H1 + off) = 0;
                    }
                }
            }
            {   // nq=1 from g2vB
                const int col2 = ((nt0 + 1) * 16 + l16) * 2;
                #pragma unroll
                for (int q = 0; q < 4; ++q) {
                    const int row = mt * 16 + l4 * 4 + q;
                    const int off = row * 1024 + (col2 ^ ((row & 7) << 4));
                    if ((mk >> ((mt * 2 + 1) * 4 + q)) & 1u) {
                        f2h2(g2vB[mt][q],
                             (unsigned short*)(smem + L_H0 + off),
                             (unsigned short*)(smem + L_H1 + off));
                    } else {
                        *(unsigned short*)(smem + L_H0 + off) = 0;
                        *(unsigned short*)(smem + L_H1 + off) = 0;
                    }
                }
            }
        }
        __syncthreads();

        // ---- S4: grad = m1 @ W1y^T (1 tile/wave) ; y -= LR*grad ; refresh y planes
        f32x4 gA = (f32x4){0.f, 0.f, 0.f, 0.f}, gAm = gA;
        {
            const char* bh = (const char*)(wsb + OFF_W1Y4);
            const char* bm = (const char*)(wsb + PH + OFF_W1Y4);
            #pragma unroll
            for (int kk = 0; kk < 16; ++kk) {
                const int cb = kk * 64 + l4 * 16;
                const int row = mt4 * 16 + l16;
                const int offA = row * 1024 + (cb ^ ((row & 7) << 4));
                f16x8 ah = *(const f16x8*)(smem + L_H0 + offA);
                f16x8 am = *(const f16x8*)(smem + L_H1 + offA);
                const size_t obA = (size_t)(nt4 * 16 + l16) * 1024 + cb;
                f16x8 bAh = *(const f16x8*)(bh + obA);
                f16x8 bAm = *(const f16x8*)(bm + obA);
                gA  = __builtin_amdgcn_mfma_f32_16x16x32_f16(ah, bAh, gA,  0, 0, 0);
                gAm = __builtin_amdgcn_mfma_f32_16x16x32_f16(ah, bAm, gAm, 0, 0, 0);
                gAm = __builtin_amdgcn_mfma_f32_16x16x32_f16(am, bAh, gAm, 0, 0, 0);
            }
        }
        #pragma unroll
        for (int q = 0; q < 4; ++q)
            ym[q] = ym[q] - LRC * (gA[q] + gAm[q] * SC12);
        #pragma unroll
        for (int q = 0; q < 4; ++q) {
            const int row = mt4 * 16 + l4 * 4 + q;
            const int col = nt4 * 16 + l16;
            const int off = row * 128 + ((col * 2) ^ ((row & 7) << 4));
            f2h2(ym[q], (unsigned short*)(smem + L_Y0 + off),
                        (unsigned short*)(smem + L_Y1 + off));
        }
    }

    // write out from fp32 register master
    #pragma unroll
    for (int q = 0; q < 4; ++q) {
        const int row = mt4 * 16 + l4 * 4 + q;
        const int col = nt4 * 16 + l16;
        out[(size_t)(r0 + row) * DYD + col] = ym[q];
    }
}

extern "C" void kernel_launch(void* const* d_in, const int* in_sizes, int n_in,
                              void* d_out, int out_size, void* d_ws, size_t ws_size,
                              hipStream_t stream) {
    const float* x  = (const float*)d_in[0];
    const int*   t  = (const int*)d_in[1];
    const float* W1 = (const float*)d_in[2];
    const float* b1 = (const float*)d_in[3];
    const float* W2 = (const float*)d_in[4];
    const float* b2 = (const float*)d_in[5];
    const float* W3 = (const float*)d_in[6];
    // d_in[7] = b3: constant offset, no effect on grad_y
    const int* steps = (const int*)d_in[8];
    float* out = (float*)d_out;
    unsigned short* wsb = (unsigned short*)d_ws;

    const int B = in_sizes[0] / DXD;
    const int nblocks = B / NROWS;

    wconv<<<(PH + 255) / 256, 256, 0, stream>>>(W1, W2, wsb);

    ebm_mfma<<<nblocks, NTHR, 0, stream>>>(x, t, W1, b1, W2, b2, W3, steps, wsb, out);
}